// Round 1
// baseline (5680.348 us; speedup 1.0000x reference)
//
#include <hip/hip_runtime.h>
#include <hip/hip_bf16.h>
#include <math.h>

// ---- model dims ----
constexpr int Bn  = 4;
constexpr int Tn  = 8192;
constexpr int Dn  = 1024;
constexpr int Pn  = 512;
constexpr int SEGn= 16;     // T/P
constexpr int Sn  = 4;
constexpr int Ln  = 4;
constexpr int NHn = 16;
constexpr int NKVn= 4;
constexpr int HDn = 64;
constexpr int Gn  = 4;      // NH/NKV
constexpr int FFn = 4096;
constexpr int KCn = 256;
constexpr int Vn  = 257;
constexpr int DHn = 512;    // conv hidden (D/2)

// ---- workspace layout (float elements). total = 19,908,096 floats = 76 MB ----
constexpr long OFF_EW  = 0;                       // 3*257*512 = 394752
constexpr long OFF_CA  = 394752;                  // B*T
constexpr long OFF_CB  = 427520;
constexpr long OFF_CC  = 460288;
constexpr long OFF_ENT = 493056;                  // B*P
constexpr long OFF_IDX = 495104;                  // B*P (int)
constexpr long OFF_XP  = 497152;                  // B*P*D = 2097152
constexpr long OFF_RL  = 2594304;                 // B*P
constexpr long OFF_SEL = 2596352;                 // B*KC (int)
constexpr long OFF_G   = 2597376;                 // B*KC
constexpr long SCR     = 2598400;
// layer-phase scratch (offsets relative to SCR):
constexpr long SC_XS   = 0;         // 1048576
constexpr long SC_H    = 1048576;   // 1048576
constexpr long SC_Q    = 2097152;   // 1048576
constexpr long SC_K    = 3145728;   // 262144
constexpr long SC_V    = 3407872;   // 262144
constexpr long SC_AOUT = 3670016;   // 1048576
constexpr long SC_AO   = 4718592;   // 1048576
constexpr long SC_H2   = 5767168;   // 1048576
constexpr long SC_GACT = 6815744;   // 4194304
constexpr long SC_UACT = 11010048;  // 4194304
constexpr long SC_FF   = 15204352;  // 1048576
// decoder-phase scratch (reuses layer region, after layers done):
constexpr long SC_PROJ = 0;         // 8388608
constexpr long SC_HMLP = 8388608;   // 524288
constexpr long SC_WIN  = 8912896;   // 8192
constexpr long SC_Y    = 8921088;   // 8388608

// ---- helpers ----
__device__ __forceinline__ float geluf(float x) {
    float x3 = x * x * x;
    return 0.5f * x * (1.f + tanhf(0.7978845608028654f * (x + 0.044715f * x3)));
}
__device__ __forceinline__ float sigmf(float x) { return 1.f / (1.f + expf(-x)); }

// block (256 threads) sum reduce; red must be __shared__ float[4]
__device__ __forceinline__ float blk_sum256(float v, float* red) {
    for (int o = 32; o > 0; o >>= 1) v += __shfl_down(v, o);
    int lane = threadIdx.x & 63, w = threadIdx.x >> 6;
    if (lane == 0) red[w] = v;
    __syncthreads();
    float r = red[0] + red[1] + red[2] + red[3];
    __syncthreads();
    return r;
}

// ---- K0: EW[dk][v][o] = sum_i emb[v,i] * w1[o,i,dk] ----
// grid (96, 17), block (16,16). c = o*3+dk, c<1536.
__global__ void k_ew(const float* __restrict__ emb, const float* __restrict__ w1,
                     float* __restrict__ EW) {
    __shared__ float As[16][17];
    __shared__ float Ws[16][17];
    int c0 = blockIdx.x * 16, v0 = blockIdx.y * 16;
    int tx = threadIdx.x, ty = threadIdx.y;
    float acc = 0.f;
    int c = c0 + tx;
    int o = c / 3, dk = c - o * 3;
    for (int k0 = 0; k0 < Dn; k0 += 16) {
        int v = v0 + ty;
        As[ty][tx] = (v < Vn) ? emb[v * Dn + k0 + tx] : 0.f;
        Ws[ty][tx] = w1[o * 3072 + (k0 + ty) * 3 + dk];
        __syncthreads();
        #pragma unroll
        for (int kk = 0; kk < 16; kk++) acc += As[ty][kk] * Ws[kk][tx];
        __syncthreads();
    }
    int v = v0 + ty;
    if (v < Vn) EW[(long)dk * (Vn * DHn) + (long)v * DHn + o] = acc;
}

// ---- K1: per (b,t): h1 column via EW lookups + gelu, reduce to 3 dots with w2 ----
// block 256 = 4 waves, one (b,t) per wave. grid = B*T/4.
__global__ void k_conv1(const int* __restrict__ tok, const float* __restrict__ EW,
                        const float* __restrict__ b1, const float* __restrict__ w2,
                        float* __restrict__ cA, float* __restrict__ cB, float* __restrict__ cC) {
    int wave = threadIdx.x >> 6, lane = threadIdx.x & 63;
    int gidx = blockIdx.x * 4 + wave;     // b*T + t
    int b = gidx / Tn, t = gidx - b * Tn;
    int tk  = tok[b * Tn + t];
    int tkm = (t > 0)      ? tok[b * Tn + t - 1] : -1;
    int tkp = (t < Tn - 1) ? tok[b * Tn + t + 1] : -1;
    const float* E0 = EW;
    const float* E1 = EW + (long)Vn * DHn;
    const float* E2 = EW + 2L * Vn * DHn;
    float a0 = 0.f, a1 = 0.f, a2 = 0.f;
    #pragma unroll
    for (int u = 0; u < DHn / 64; u++) {
        int o = lane + u * 64;
        float s = b1[o] + E1[tk * DHn + o];
        if (tkm >= 0) s += E0[tkm * DHn + o];
        if (tkp >= 0) s += E2[tkp * DHn + o];
        float hg = geluf(s);
        a0 += hg * w2[o * 3 + 0];
        a1 += hg * w2[o * 3 + 1];
        a2 += hg * w2[o * 3 + 2];
    }
    for (int o = 32; o > 0; o >>= 1) {
        a0 += __shfl_down(a0, o); a1 += __shfl_down(a1, o); a2 += __shfl_down(a2, o);
    }
    if (lane == 0) { cA[gidx] = a0; cB[gidx] = a1; cC[gidx] = a2; }
}

// ---- K2: lg per token -> per-patch softmax -> ent, idx ----
__global__ void k_patchstats(const float* __restrict__ cA, const float* __restrict__ cB,
                             const float* __restrict__ cC, const float* __restrict__ b2,
                             float* __restrict__ ent_out, int* __restrict__ idx_out) {
    int pid = blockIdx.x * blockDim.x + threadIdx.x;   // b*P + p
    if (pid >= Bn * Pn) return;
    int b = pid / Pn, p = pid - b * Pn;
    float lgv[SEGn];
    float m = -3.4e38f;
    for (int s = 0; s < SEGn; s++) {
        int t = p * SEGn + s;
        float v = b2[0] + cB[b * Tn + t];
        if (t > 0)      v += cA[b * Tn + t - 1];
        if (t < Tn - 1) v += cC[b * Tn + t + 1];
        lgv[s] = v; m = fmaxf(m, v);
    }
    float Z = 0.f;
    for (int s = 0; s < SEGn; s++) { lgv[s] = expf(lgv[s] - m); Z += lgv[s]; }
    float inv = 1.f / Z;
    float bp = 0.f, en = 0.f;
    for (int s = 0; s < SEGn; s++) {
        float w = lgv[s] * inv;
        bp += w * (float)(p * SEGn + s);
        en -= w * logf(fmaxf(w, 1e-8f));
    }
    en *= (1.f / 2.772588722239781f);   // / ln(16)
    ent_out[pid] = en;
    int ix = (int)bp;                    // trunc == floor (bp>=0)
    ix = ix < 0 ? 0 : (ix > Tn - 1 ? Tn - 1 : ix);
    idx_out[pid] = ix;
}

// ---- K3: xp[b,p,:] = rmsnorm(emb[tok[b, idx[b,p]]], enc_norm_w). block per row ----
__global__ void k_xp(const int* __restrict__ tok, const int* __restrict__ idx,
                     const float* __restrict__ emb, const float* __restrict__ nw,
                     float* __restrict__ xp) {
    int pid = blockIdx.x;
    int b = pid / Pn;
    int tk = tok[b * Tn + idx[pid]];
    const float* row = emb + (long)tk * Dn;
    __shared__ float red[4];
    float v[4]; float ss = 0.f;
    #pragma unroll
    for (int j = 0; j < 4; j++) { v[j] = row[threadIdx.x + j * 256]; ss += v[j] * v[j]; }
    ss = blk_sum256(ss, red);
    float sc = 1.f / sqrtf(ss * (1.f / Dn) + 1e-6f);
    #pragma unroll
    for (int j = 0; j < 4; j++) {
        int d = threadIdx.x + j * 256;
        xp[(long)pid * Dn + d] = v[j] * sc * nw[d];
    }
}

// ---- K4: rl[b,p] = xp[b,p,:]·rw + ent. block per row ----
__global__ void k_router(const float* __restrict__ xp, const float* __restrict__ rw,
                         const float* __restrict__ ent, float* __restrict__ rl) {
    int pid = blockIdx.x;
    const float* xr = xp + (long)pid * Dn;
    __shared__ float red[4];
    float s = 0.f;
    #pragma unroll
    for (int j = 0; j < 4; j++) { int d = threadIdx.x + j * 256; s += xr[d] * rw[d]; }
    s = blk_sum256(s, red);
    if (threadIdx.x == 0) rl[pid] = s + ent[pid];
}

// ---- K5: exact top-k (KC of P) with jax tie semantics, output ascending by index ----
// grid = B, block = 512
__global__ void k_topk(const float* __restrict__ rl, int* __restrict__ sel, float* __restrict__ g) {
    int b = blockIdx.x, p = threadIdx.x;
    __shared__ float vals[Pn];
    __shared__ int flag[Pn];
    float v = rl[b * Pn + p];
    vals[p] = v;
    __syncthreads();
    int rank = 0;
    for (int q = 0; q < Pn; q++) {
        float vq = vals[q];
        rank += (vq > v || (vq == v && q < p)) ? 1 : 0;
    }
    int selected = rank < KCn ? 1 : 0;
    flag[p] = selected;
    __syncthreads();
    if (selected) {
        int pos = 0;
        for (int q = 0; q < p; q++) pos += flag[q];
        sel[b * KCn + pos] = p;
        g[b * KCn + pos] = sigmf(v);
    }
}

// ---- K6: gather xs = xp[b, sel], h = rmsnorm(xs, ln1). block per (b,j) ----
__global__ void k_gather_ln1(const float* __restrict__ xp, const int* __restrict__ sel,
                             const float* __restrict__ w, float* __restrict__ xs,
                             float* __restrict__ h) {
    int r = blockIdx.x;            // b*KC + j
    int b = r / KCn;
    int p = sel[r];
    const float* src = xp + ((long)b * Pn + p) * Dn;
    __shared__ float red[4];
    float v[4]; float ss = 0.f;
    #pragma unroll
    for (int j = 0; j < 4; j++) { v[j] = src[threadIdx.x + j * 256]; ss += v[j] * v[j]; }
    ss = blk_sum256(ss, red);
    float sc = 1.f / sqrtf(ss * (1.f / Dn) + 1e-6f);
    #pragma unroll
    for (int j = 0; j < 4; j++) {
        int d = threadIdx.x + j * 256;
        xs[(long)r * Dn + d] = v[j];
        h[(long)r * Dn + d] = v[j] * sc * w[d];
    }
}

// ---- generic fp32 GEMM: C[M,N] = A[M,K] @ W[K,N] (+bias)(+act). ----
// grid (ceil(N/64), M/64), block 256. act: 0 none, 1 gelu.
__global__ void k_gemm(const float* __restrict__ A, const float* __restrict__ Wm,
                       float* __restrict__ Cmat, const float* __restrict__ bias,
                       int M, int N, int K, int act) {
    __shared__ float As[16][68];
    __shared__ float Ws[16][68];
    int n0 = blockIdx.x * 64, m0 = blockIdx.y * 64;
    int tid = threadIdx.x;
    int tx = tid & 15, ty = tid >> 4;
    float acc[4][4] = {};
    for (int k0 = 0; k0 < K; k0 += 16) {
        {
            int lin = tid * 4; int r = lin >> 4, c = lin & 15;
            const float* ap = A + (long)(m0 + r) * K + k0 + c;
            As[c + 0][r] = ap[0]; As[c + 1][r] = ap[1];
            As[c + 2][r] = ap[2]; As[c + 3][r] = ap[3];
        }
        {
            int lin = tid * 4; int r = lin >> 6, c = lin & 63;
            int n = n0 + c;
            const float* wp = Wm + (long)(k0 + r) * N + n;
            Ws[r][c + 0] = (n + 0 < N) ? wp[0] : 0.f;
            Ws[r][c + 1] = (n + 1 < N) ? wp[1] : 0.f;
            Ws[r][c + 2] = (n + 2 < N) ? wp[2] : 0.f;
            Ws[r][c + 3] = (n + 3 < N) ? wp[3] : 0.f;
        }
        __syncthreads();
        #pragma unroll
        for (int kk = 0; kk < 16; kk++) {
            float a[4], bb[4];
            #pragma unroll
            for (int i = 0; i < 4; i++) a[i] = As[kk][ty * 4 + i];
            #pragma unroll
            for (int j = 0; j < 4; j++) bb[j] = Ws[kk][tx * 4 + j];
            #pragma unroll
            for (int i = 0; i < 4; i++)
                #pragma unroll
                for (int j = 0; j < 4; j++) acc[i][j] += a[i] * bb[j];
        }
        __syncthreads();
    }
    #pragma unroll
    for (int i = 0; i < 4; i++) {
        int m = m0 + ty * 4 + i;
        if (m >= M) continue;
        #pragma unroll
        for (int j = 0; j < 4; j++) {
            int n = n0 + tx * 4 + j;
            if (n < N) {
                float vv = acc[i][j];
                if (bias) vv += bias[n];
                if (act == 1) vv = geluf(vv);
                Cmat[(long)m * N + n] = vv;
            }
        }
    }
}

// ---- RoPE in-place on (B*KC, nh*64), positions = sel[row] ----
__global__ void k_rope(float* __restrict__ buf, const int* __restrict__ sel, int nh) {
    int tid = blockIdx.x * blockDim.x + threadIdx.x;
    int total = Bn * KCn * nh * 32;
    if (tid >= total) return;
    int d = tid & 31;
    int h = (tid >> 5) % nh;
    int r = tid / (32 * nh);
    int pos = sel[r];
    float theta = powf(10000.f, -(float)(2 * d) / 64.f);
    float ang = (float)pos * theta;
    float c = cosf(ang), s = sinf(ang);
    long base = (long)r * (nh * 64) + h * 64 + d;
    float x1 = buf[base], x2 = buf[base + 32];
    buf[base]      = x1 * c - x2 * s;
    buf[base + 32] = x2 * c + x1 * s;
}

// ---- fused attention: one block per (b,h,i): scores, softmax, PV ----
// grid = B*NH*KC, block 256
__global__ void k_attn(const float* __restrict__ q, const float* __restrict__ k,
                       const float* __restrict__ v, float* __restrict__ aout) {
    int blk = blockIdx.x;
    int i = blk & (KCn - 1);
    int h = (blk >> 8) & (NHn - 1);
    int b = blk >> 12;
    int hk = h >> 2;                // h / G
    int tid = threadIdx.x;
    __shared__ float qs[HDn];
    __shared__ float probs[KCn];
    __shared__ float red[4];
    __shared__ float pr[4][HDn];
    if (tid < HDn) qs[tid] = q[((long)(b * KCn + i)) * (NHn * HDn) + h * HDn + tid];
    __syncthreads();
    int j = tid;
    const float* kr = k + ((long)(b * KCn + j)) * (NKVn * HDn) + hk * HDn;
    float dot = 0.f;
    #pragma unroll
    for (int d = 0; d < HDn; d++) dot += qs[d] * kr[d];
    float s = (j <= i) ? dot * 0.125f : -1e30f;
    float m = s;
    for (int o = 32; o > 0; o >>= 1) m = fmaxf(m, __shfl_down(m, o));
    int lane = tid & 63, w = tid >> 6;
    if (lane == 0) red[w] = m;
    __syncthreads();
    m = fmaxf(fmaxf(red[0], red[1]), fmaxf(red[2], red[3]));
    __syncthreads();
    float pe = expf(s - m);
    float z = pe;
    for (int o = 32; o > 0; o >>= 1) z += __shfl_down(z, o);
    if (lane == 0) red[w] = z;
    __syncthreads();
    z = red[0] + red[1] + red[2] + red[3];
    probs[tid] = pe / z;
    __syncthreads();
    int d = tid & 63, ch = tid >> 6;
    float part = 0.f;
    for (int jj = ch * 64; jj < ch * 64 + 64; jj++)
        part += probs[jj] * v[((long)(b * KCn + jj)) * (NKVn * HDn) + hk * HDn + d];
    pr[ch][d] = part;
    __syncthreads();
    if (tid < HDn) {
        float o = pr[0][tid] + pr[1][tid] + pr[2][tid] + pr[3][tid];
        aout[((long)(b * KCn + i)) * (NHn * HDn) + h * HDn + tid] = o;
    }
}

// ---- x2 = xs + ao; h2 = rmsnorm(x2, ln2). block per row ----
__global__ void k_add_ln2(const float* __restrict__ xs, const float* __restrict__ ao,
                          const float* __restrict__ w, float* __restrict__ h2) {
    int r = blockIdx.x;
    __shared__ float red[4];
    float v[4]; float ss = 0.f;
    #pragma unroll
    for (int j = 0; j < 4; j++) {
        int d = threadIdx.x + j * 256;
        float x = xs[(long)r * Dn + d] + ao[(long)r * Dn + d];
        v[j] = x; ss += x * x;
    }
    ss = blk_sum256(ss, red);
    float sc = 1.f / sqrtf(ss * (1.f / Dn) + 1e-6f);
    #pragma unroll
    for (int j = 0; j < 4; j++) {
        int d = threadIdx.x + j * 256;
        h2[(long)r * Dn + d] = v[j] * sc * w[d];
    }
}

// ---- gact = silu(gact)*uact ----
__global__ void k_silu_mul(float* __restrict__ gact, const float* __restrict__ uact, int n) {
    int i = blockIdx.x * blockDim.x + threadIdx.x;
    if (i < n) { float x = gact[i]; gact[i] = x * sigmf(x) * uact[i]; }
}

// ---- xp[b, sel[b,j], :] += g * (ao + ff). block per (b,j) ----
__global__ void k_scatter(float* __restrict__ xp, const float* __restrict__ ao,
                          const float* __restrict__ ff, const float* __restrict__ g,
                          const int* __restrict__ sel) {
    int r = blockIdx.x;
    int b = r / KCn;
    int p = sel[r];
    float gg = g[r];
    float* dst = xp + ((long)b * Pn + p) * Dn;
    #pragma unroll
    for (int j = 0; j < 4; j++) {
        int d = threadIdx.x + j * 256;
        dst[d] += gg * (ao[(long)r * Dn + d] + ff[(long)r * Dn + d]);
    }
}

// ---- win = sigmoid(hmlp @ w2 + b2). thread per (row, s) ----
__global__ void k_win(const float* __restrict__ hmlp, const float* __restrict__ w2,
                      const float* __restrict__ b2, float* __restrict__ win) {
    int tid = blockIdx.x * blockDim.x + threadIdx.x;
    if (tid >= Bn * Pn * Sn) return;
    int s = tid & 3; int r = tid >> 2;
    float acc = b2[s];
    const float* hr = hmlp + (long)r * 256;
    for (int i = 0; i < 256; i++) acc += hr[i] * w2[i * 4 + s];
    win[tid] = sigmf(acc);
}

// ---- y = rmsnorm(proj*win, dec_norm_w). block per row (8192 rows) ----
__global__ void k_dec_norm(const float* __restrict__ proj, const float* __restrict__ win,
                           const float* __restrict__ w, float* __restrict__ y) {
    int r = blockIdx.x;
    float wv = win[r];
    __shared__ float red[4];
    float v[4]; float ss = 0.f;
    #pragma unroll
    for (int j = 0; j < 4; j++) {
        int d = threadIdx.x + j * 256;
        float x = proj[(long)r * Dn + d] * wv;
        v[j] = x; ss += x * x;
    }
    ss = blk_sum256(ss, red);
    float sc = 1.f / sqrtf(ss * (1.f / Dn) + 1e-6f);
    #pragma unroll
    for (int j = 0; j < 4; j++) {
        int d = threadIdx.x + j * 256;
        y[(long)r * Dn + d] = v[j] * sc * w[d];
    }
}

extern "C" void kernel_launch(void* const* d_in, const int* in_sizes, int n_in,
                              void* d_out, int out_size, void* d_ws, size_t ws_size,
                              hipStream_t stream) {
    const int*   tokens     = (const int*)  d_in[0];
    const float* emb        = (const float*)d_in[1];
    const float* bp_w1      = (const float*)d_in[2];
    const float* bp_b1      = (const float*)d_in[3];
    const float* bp_w2      = (const float*)d_in[4];
    const float* bp_b2      = (const float*)d_in[5];
    const float* enc_norm_w = (const float*)d_in[6];
    const float* router_w   = (const float*)d_in[7];
    const float* ln1_w      = (const float*)d_in[8];
    const float* ln2_w      = (const float*)d_in[9];
    const float* q_w        = (const float*)d_in[10];
    const float* k_w        = (const float*)d_in[11];
    const float* v_w        = (const float*)d_in[12];
    const float* o_w        = (const float*)d_in[13];
    const float* gate_w     = (const float*)d_in[14];
    const float* up_w       = (const float*)d_in[15];
    const float* down_w     = (const float*)d_in[16];
    const float* dec_proj_w = (const float*)d_in[17];
    const float* dec_proj_b = (const float*)d_in[18];
    const float* dec_mlp_w1 = (const float*)d_in[19];
    const float* dec_mlp_b1 = (const float*)d_in[20];
    const float* dec_mlp_w2 = (const float*)d_in[21];
    const float* dec_mlp_b2 = (const float*)d_in[22];
    const float* dec_norm_w = (const float*)d_in[23];
    const float* head_w     = (const float*)d_in[24];
    float* out = (float*)d_out;

    float* W = (float*)d_ws;
    float* EW   = W + OFF_EW;
    float* cA   = W + OFF_CA;
    float* cB   = W + OFF_CB;
    float* cC   = W + OFF_CC;
    float* ent  = W + OFF_ENT;
    int*   idxb = (int*)(W + OFF_IDX);
    float* xp   = W + OFF_XP;
    float* rl   = W + OFF_RL;
    int*   sel  = (int*)(W + OFF_SEL);
    float* g    = W + OFF_G;
    float* scr  = W + SCR;
    float* xs   = scr + SC_XS;
    float* h    = scr + SC_H;
    float* qb   = scr + SC_Q;
    float* kb   = scr + SC_K;
    float* vb   = scr + SC_V;
    float* aout = scr + SC_AOUT;
    float* ao   = scr + SC_AO;
    float* h2   = scr + SC_H2;
    float* gact = scr + SC_GACT;
    float* uact = scr + SC_UACT;
    float* ffb  = scr + SC_FF;
    float* proj = scr + SC_PROJ;
    float* hmlp = scr + SC_HMLP;
    float* win  = scr + SC_WIN;
    float* y    = scr + SC_Y;

    // byte-patch encoder
    k_ew<<<dim3(96, 17), dim3(16, 16), 0, stream>>>(emb, bp_w1, EW);
    k_conv1<<<Bn * Tn / 4, 256, 0, stream>>>(tokens, EW, bp_b1, bp_w2, cA, cB, cC);
    k_patchstats<<<(Bn * Pn + 255) / 256, 256, 0, stream>>>(cA, cB, cC, bp_b2, ent, idxb);
    k_xp<<<Bn * Pn, 256, 0, stream>>>(tokens, idxb, emb, enc_norm_w, xp);

    for (int l = 0; l < Ln; l++) {
        k_router<<<Bn * Pn, 256, 0, stream>>>(xp, router_w + (long)l * Dn, ent, rl);
        k_topk<<<Bn, Pn, 0, stream>>>(rl, sel, g);
        k_gather_ln1<<<Bn * KCn, 256, 0, stream>>>(xp, sel, ln1_w + (long)l * Dn, xs, h);
        k_gemm<<<dim3(16, 16), 256, 0, stream>>>(h, q_w + (long)l * Dn * Dn, qb, nullptr, 1024, 1024, 1024, 0);
        k_gemm<<<dim3(4, 16),  256, 0, stream>>>(h, k_w + (long)l * Dn * 256, kb, nullptr, 1024, 256, 1024, 0);
        k_gemm<<<dim3(4, 16),  256, 0, stream>>>(h, v_w + (long)l * Dn * 256, vb, nullptr, 1024, 256, 1024, 0);
        k_rope<<<(Bn * KCn * NHn * 32 + 255) / 256, 256, 0, stream>>>(qb, sel, NHn);
        k_rope<<<(Bn * KCn * NKVn * 32 + 255) / 256, 256, 0, stream>>>(kb, sel, NKVn);
        k_attn<<<Bn * NHn * KCn, 256, 0, stream>>>(qb, kb, vb, aout);
        k_gemm<<<dim3(16, 16), 256, 0, stream>>>(aout, o_w + (long)l * Dn * Dn, ao, nullptr, 1024, 1024, 1024, 0);
        k_add_ln2<<<Bn * KCn, 256, 0, stream>>>(xs, ao, ln2_w + (long)l * Dn, h2);
        k_gemm<<<dim3(64, 16), 256, 0, stream>>>(h2, gate_w + (long)l * Dn * FFn, gact, nullptr, 1024, 4096, 1024, 0);
        k_gemm<<<dim3(64, 16), 256, 0, stream>>>(h2, up_w + (long)l * Dn * FFn, uact, nullptr, 1024, 4096, 1024, 0);
        k_silu_mul<<<(Bn * KCn * FFn + 255) / 256, 256, 0, stream>>>(gact, uact, Bn * KCn * FFn);
        k_gemm<<<dim3(16, 16), 256, 0, stream>>>(gact, down_w + (long)l * FFn * Dn, ffb, nullptr, 1024, 1024, 4096, 0);
        k_scatter<<<Bn * KCn, 256, 0, stream>>>(xp, ao, ffb, g, sel);
    }

    // decoder
    k_gemm<<<dim3(64, 32), 256, 0, stream>>>(xp, dec_proj_w, proj, dec_proj_b, 2048, 4096, 1024, 0);
    k_gemm<<<dim3(4, 32),  256, 0, stream>>>(xp, dec_mlp_w1, hmlp, dec_mlp_b1, 2048, 256, 1024, 1);
    k_win<<<(Bn * Pn * Sn + 255) / 256, 256, 0, stream>>>(hmlp, dec_mlp_w2, dec_mlp_b2, win);
    k_dec_norm<<<Bn * Pn * Sn, 256, 0, stream>>>(proj, win, dec_norm_w, y);
    k_gemm<<<dim3(5, 128), 256, 0, stream>>>(y, head_w, out, nullptr, 8192, 257, 1024, 0);
}

// Round 2
// 4242.402 us; speedup vs baseline: 1.3389x; 1.3389x over previous
//
#include <hip/hip_runtime.h>
#include <hip/hip_bf16.h>
#include <math.h>

// ---- model dims ----
constexpr int Bn  = 4;
constexpr int Tn  = 8192;
constexpr int Dn  = 1024;
constexpr int Pn  = 512;
constexpr int SEGn= 16;     // T/P
constexpr int Sn  = 4;
constexpr int Ln  = 4;
constexpr int NHn = 16;
constexpr int NKVn= 4;
constexpr int HDn = 64;
constexpr int FFn = 4096;
constexpr int KCn = 256;
constexpr int Vn  = 257;
constexpr int DHn = 512;    // conv hidden (D/2)

// ---- workspace layout (float elements). total = 19,908,096 floats = 76 MB ----
constexpr long OFF_EW  = 0;                       // 3*257*512 = 394752
constexpr long OFF_CA  = 394752;                  // B*T
constexpr long OFF_CB  = 427520;
constexpr long OFF_CC  = 460288;
constexpr long OFF_ENT = 493056;                  // B*P
constexpr long OFF_IDX = 495104;                  // B*P (int)
constexpr long OFF_XP  = 497152;                  // B*P*D = 2097152
constexpr long OFF_RL  = 2594304;                 // B*P
constexpr long OFF_SEL = 2596352;                 // B*KC (int)
constexpr long OFF_G   = 2597376;                 // B*KC
constexpr long SCR     = 2598400;
// layer-phase scratch (offsets relative to SCR):
constexpr long SC_XS   = 0;         // 1048576
constexpr long SC_H    = 1048576;   // 1048576
constexpr long SC_Q    = 2097152;   // 1048576
constexpr long SC_K    = 3145728;   // 262144
constexpr long SC_V    = 3407872;   // 262144
constexpr long SC_AOUT = 3670016;   // 1048576
constexpr long SC_AO   = 4718592;   // 1048576
constexpr long SC_H2   = 5767168;   // 1048576
constexpr long SC_GACT = 6815744;   // 4194304
constexpr long SC_UACT = 11010048;  // 4194304
constexpr long SC_FF   = 15204352;  // 1048576
// decoder-phase scratch (reuses layer region, after layers done):
constexpr long SC_PROJ = 0;         // 8388608
constexpr long SC_HMLP = 8388608;   // 524288
constexpr long SC_WIN  = 8912896;   // 8192
constexpr long SC_Y    = 8921088;   // 8388608

typedef __attribute__((ext_vector_type(8))) short short8;
typedef __attribute__((ext_vector_type(4))) float floatx4;

// ---- helpers ----
__device__ __forceinline__ float geluf(float x) {
    float x3 = x * x * x;
    return 0.5f * x * (1.f + tanhf(0.7978845608028654f * (x + 0.044715f * x3)));
}
__device__ __forceinline__ float sigmf(float x) { return 1.f / (1.f + expf(-x)); }

// fp32 -> bf16 hi/lo split (truncation; x ~= hi + lo, err ~2^-17 rel)
__device__ __forceinline__ void cvt_hilo(float x, unsigned short& h, unsigned short& l) {
    unsigned u = __float_as_uint(x);
    h = (unsigned short)(u >> 16);
    float r = x - __uint_as_float(u & 0xffff0000u);
    l = (unsigned short)(__float_as_uint(r) >> 16);
}

// block (256 threads) sum reduce; red must be __shared__ float[4]
__device__ __forceinline__ float blk_sum256(float v, float* red) {
    for (int o = 32; o > 0; o >>= 1) v += __shfl_down(v, o);
    int lane = threadIdx.x & 63, w = threadIdx.x >> 6;
    if (lane == 0) red[w] = v;
    __syncthreads();
    float r = red[0] + red[1] + red[2] + red[3];
    __syncthreads();
    return r;
}

// ---- K0: EW[dk][v][o] = sum_i emb[v,i] * w1[o,i,dk] ----
// grid (96, 17), block (16,16). c = o*3+dk, c<1536.
__global__ void k_ew(const float* __restrict__ emb, const float* __restrict__ w1,
                     float* __restrict__ EW) {
    __shared__ float As[16][17];
    __shared__ float Ws[16][17];
    int c0 = blockIdx.x * 16, v0 = blockIdx.y * 16;
    int tx = threadIdx.x, ty = threadIdx.y;
    float acc = 0.f;
    int c = c0 + tx;
    int o = c / 3, dk = c - o * 3;
    for (int k0 = 0; k0 < Dn; k0 += 16) {
        int v = v0 + ty;
        As[ty][tx] = (v < Vn) ? emb[v * Dn + k0 + tx] : 0.f;
        Ws[ty][tx] = w1[o * 3072 + (k0 + ty) * 3 + dk];
        __syncthreads();
        #pragma unroll
        for (int kk = 0; kk < 16; kk++) acc += As[ty][kk] * Ws[kk][tx];
        __syncthreads();
    }
    int v = v0 + ty;
    if (v < Vn) EW[(long)dk * (Vn * DHn) + (long)v * DHn + o] = acc;
}

// ---- K1: per (b,t): h1 column via EW lookups + gelu, reduce to 3 dots with w2 ----
__global__ void k_conv1(const int* __restrict__ tok, const float* __restrict__ EW,
                        const float* __restrict__ b1, const float* __restrict__ w2,
                        float* __restrict__ cA, float* __restrict__ cB, float* __restrict__ cC) {
    int wave = threadIdx.x >> 6, lane = threadIdx.x & 63;
    int gidx = blockIdx.x * 4 + wave;     // b*T + t
    int b = gidx / Tn, t = gidx - b * Tn;
    int tk  = tok[b * Tn + t];
    int tkm = (t > 0)      ? tok[b * Tn + t - 1] : -1;
    int tkp = (t < Tn - 1) ? tok[b * Tn + t + 1] : -1;
    const float* E0 = EW;
    const float* E1 = EW + (long)Vn * DHn;
    const float* E2 = EW + 2L * Vn * DHn;
    float a0 = 0.f, a1 = 0.f, a2 = 0.f;
    #pragma unroll
    for (int u = 0; u < DHn / 64; u++) {
        int o = lane + u * 64;
        float s = b1[o] + E1[tk * DHn + o];
        if (tkm >= 0) s += E0[tkm * DHn + o];
        if (tkp >= 0) s += E2[tkp * DHn + o];
        float hg = geluf(s);
        a0 += hg * w2[o * 3 + 0];
        a1 += hg * w2[o * 3 + 1];
        a2 += hg * w2[o * 3 + 2];
    }
    for (int o = 32; o > 0; o >>= 1) {
        a0 += __shfl_down(a0, o); a1 += __shfl_down(a1, o); a2 += __shfl_down(a2, o);
    }
    if (lane == 0) { cA[gidx] = a0; cB[gidx] = a1; cC[gidx] = a2; }
}

// ---- K2: lg per token -> per-patch softmax -> ent, idx ----
__global__ void k_patchstats(const float* __restrict__ cA, const float* __restrict__ cB,
                             const float* __restrict__ cC, const float* __restrict__ b2,
                             float* __restrict__ ent_out, int* __restrict__ idx_out) {
    int pid = blockIdx.x * blockDim.x + threadIdx.x;   // b*P + p
    if (pid >= Bn * Pn) return;
    int b = pid / Pn, p = pid - b * Pn;
    float lgv[SEGn];
    float m = -3.4e38f;
    for (int s = 0; s < SEGn; s++) {
        int t = p * SEGn + s;
        float v = b2[0] + cB[b * Tn + t];
        if (t > 0)      v += cA[b * Tn + t - 1];
        if (t < Tn - 1) v += cC[b * Tn + t + 1];
        lgv[s] = v; m = fmaxf(m, v);
    }
    float Z = 0.f;
    for (int s = 0; s < SEGn; s++) { lgv[s] = expf(lgv[s] - m); Z += lgv[s]; }
    float inv = 1.f / Z;
    float bp = 0.f, en = 0.f;
    for (int s = 0; s < SEGn; s++) {
        float w = lgv[s] * inv;
        bp += w * (float)(p * SEGn + s);
        en -= w * logf(fmaxf(w, 1e-8f));
    }
    en *= (1.f / 2.772588722239781f);   // / ln(16)
    ent_out[pid] = en;
    int ix = (int)bp;
    ix = ix < 0 ? 0 : (ix > Tn - 1 ? Tn - 1 : ix);
    idx_out[pid] = ix;
}

// ---- K3: xp[b,p,:] = rmsnorm(emb[tok[b, idx[b,p]]], enc_norm_w). block per row ----
__global__ void k_xp(const int* __restrict__ tok, const int* __restrict__ idx,
                     const float* __restrict__ emb, const float* __restrict__ nw,
                     float* __restrict__ xp) {
    int pid = blockIdx.x;
    int b = pid / Pn;
    int tk = tok[b * Tn + idx[pid]];
    const float* row = emb + (long)tk * Dn;
    __shared__ float red[4];
    float v[4]; float ss = 0.f;
    #pragma unroll
    for (int j = 0; j < 4; j++) { v[j] = row[threadIdx.x + j * 256]; ss += v[j] * v[j]; }
    ss = blk_sum256(ss, red);
    float sc = 1.f / sqrtf(ss * (1.f / Dn) + 1e-6f);
    #pragma unroll
    for (int j = 0; j < 4; j++) {
        int d = threadIdx.x + j * 256;
        xp[(long)pid * Dn + d] = v[j] * sc * nw[d];
    }
}

// ---- K4: rl[b,p] = xp[b,p,:]·rw + ent. block per row ----
__global__ void k_router(const float* __restrict__ xp, const float* __restrict__ rw,
                         const float* __restrict__ ent, float* __restrict__ rl) {
    int pid = blockIdx.x;
    const float* xr = xp + (long)pid * Dn;
    __shared__ float red[4];
    float s = 0.f;
    #pragma unroll
    for (int j = 0; j < 4; j++) { int d = threadIdx.x + j * 256; s += xr[d] * rw[d]; }
    s = blk_sum256(s, red);
    if (threadIdx.x == 0) rl[pid] = s + ent[pid];
}

// ---- K5: exact top-k (KC of P) with jax tie semantics, output ascending by index ----
__global__ void k_topk(const float* __restrict__ rl, int* __restrict__ sel, float* __restrict__ g) {
    int b = blockIdx.x, p = threadIdx.x;
    __shared__ float vals[Pn];
    __shared__ int flag[Pn];
    float v = rl[b * Pn + p];
    vals[p] = v;
    __syncthreads();
    int rank = 0;
    for (int q = 0; q < Pn; q++) {
        float vq = vals[q];
        rank += (vq > v || (vq == v && q < p)) ? 1 : 0;
    }
    int selected = rank < KCn ? 1 : 0;
    flag[p] = selected;
    __syncthreads();
    if (selected) {
        int pos = 0;
        for (int q = 0; q < p; q++) pos += flag[q];
        sel[b * KCn + pos] = p;
        g[b * KCn + pos] = sigmf(v);
    }
}

// ---- K6: gather xs = xp[b, sel], h = rmsnorm(xs, ln1). block per (b,j) ----
__global__ void k_gather_ln1(const float* __restrict__ xp, const int* __restrict__ sel,
                             const float* __restrict__ w, float* __restrict__ xs,
                             float* __restrict__ h) {
    int r = blockIdx.x;            // b*KC + j
    int b = r / KCn;
    int p = sel[r];
    const float* src = xp + ((long)b * Pn + p) * Dn;
    __shared__ float red[4];
    float v[4]; float ss = 0.f;
    #pragma unroll
    for (int j = 0; j < 4; j++) { v[j] = src[threadIdx.x + j * 256]; ss += v[j] * v[j]; }
    ss = blk_sum256(ss, red);
    float sc = 1.f / sqrtf(ss * (1.f / Dn) + 1e-6f);
    #pragma unroll
    for (int j = 0; j < 4; j++) {
        int d = threadIdx.x + j * 256;
        xs[(long)r * Dn + d] = v[j];
        h[(long)r * Dn + d] = v[j] * sc * w[d];
    }
}

// ---- MFMA GEMM, fp32-accurate via bf16 hi/lo x3: C[M,N] = A[M,K] @ W[K,N] (+bias)(+act) ----
// grid (ceil(N/128), M/128), block 256 (4 waves, 2x2 of 64x64). BK=32.
// Requires M%128==0, K%32==0. N arbitrary (scalar B path + store guard).
constexpr int RS = 40;  // LDS row stride (bf16 elems): pad 32->40 => frag reads 2-way bank alias (free, m136)
__global__ __launch_bounds__(256) void k_mfma(const float* __restrict__ A, const float* __restrict__ Wm,
                       float* __restrict__ Cmat, const float* __restrict__ bias,
                       int M, int N, int K, int act) {
    __shared__ unsigned short Ah[128 * RS], Al[128 * RS], Bh[128 * RS], Bl[128 * RS];
    int tid = threadIdx.x;
    int m0 = blockIdx.y * 128, n0 = blockIdx.x * 128;
    int lane = tid & 63, wid = tid >> 6;
    int wm = (wid & 1) * 64, wn = (wid >> 1) * 64;
    int quad = lane >> 4, l16 = lane & 15;
    bool bfast = ((N & 3) == 0) && (n0 + 128 <= N);
    floatx4 acc[4][4];
    #pragma unroll
    for (int i = 0; i < 4; i++)
        #pragma unroll
        for (int j = 0; j < 4; j++) acc[i][j] = (floatx4){0.f, 0.f, 0.f, 0.f};

    int arow = tid >> 3, ak4 = (tid & 7) * 4;       // A: 32 rows x 8 float4 per pass, 4 passes
    int bkb = (tid >> 5) * 4, bn4 = (tid & 31) * 4; // B: 4(k) x 4(n) micro-tile per thread

    for (int k0 = 0; k0 < K; k0 += 32) {
        // stage A [128 x 32] fp32 -> bf16 hi/lo
        #pragma unroll
        for (int r4 = 0; r4 < 4; r4++) {
            int row = arow + r4 * 32;
            const float4 v = *(const float4*)(A + (long)(m0 + row) * K + k0 + ak4);
            unsigned short h0, h1, h2, h3, l0, l1, l2, l3;
            cvt_hilo(v.x, h0, l0); cvt_hilo(v.y, h1, l1);
            cvt_hilo(v.z, h2, l2); cvt_hilo(v.w, h3, l3);
            *(ushort4*)&Ah[row * RS + ak4] = make_ushort4(h0, h1, h2, h3);
            *(ushort4*)&Al[row * RS + ak4] = make_ushort4(l0, l1, l2, l3);
        }
        // stage B [32 x 128] -> transposed LDS [n][k]
        {
            float v[4][4];
            if (bfast) {
                #pragma unroll
                for (int i = 0; i < 4; i++) {
                    float4 t = *(const float4*)(Wm + (long)(k0 + bkb + i) * N + n0 + bn4);
                    v[i][0] = t.x; v[i][1] = t.y; v[i][2] = t.z; v[i][3] = t.w;
                }
            } else {
                #pragma unroll
                for (int i = 0; i < 4; i++)
                    #pragma unroll
                    for (int j = 0; j < 4; j++) {
                        int n = n0 + bn4 + j;
                        v[i][j] = (n < N) ? Wm[(long)(k0 + bkb + i) * N + n] : 0.f;
                    }
            }
            #pragma unroll
            for (int j = 0; j < 4; j++) {
                unsigned short h[4], l[4];
                #pragma unroll
                for (int i = 0; i < 4; i++) cvt_hilo(v[i][j], h[i], l[i]);
                *(ushort4*)&Bh[(bn4 + j) * RS + bkb] = make_ushort4(h[0], h[1], h[2], h[3]);
                *(ushort4*)&Bl[(bn4 + j) * RS + bkb] = make_ushort4(l[0], l[1], l[2], l[3]);
            }
        }
        __syncthreads();
        short8 ah[4], al2[4], bh[4], bl2[4];
        #pragma unroll
        for (int i = 0; i < 4; i++) {
            int r = wm + i * 16 + l16;
            ah[i]  = *(const short8*)&Ah[r * RS + quad * 8];
            al2[i] = *(const short8*)&Al[r * RS + quad * 8];
        }
        #pragma unroll
        for (int j = 0; j < 4; j++) {
            int c = wn + j * 16 + l16;
            bh[j]  = *(const short8*)&Bh[c * RS + quad * 8];
            bl2[j] = *(const short8*)&Bl[c * RS + quad * 8];
        }
        #pragma unroll
        for (int i = 0; i < 4; i++)
            #pragma unroll
            for (int j = 0; j < 4; j++) {
                acc[i][j] = __builtin_amdgcn_mfma_f32_16x16x32_bf16(ah[i],  bh[j],  acc[i][j], 0, 0, 0);
                acc[i][j] = __builtin_amdgcn_mfma_f32_16x16x32_bf16(ah[i],  bl2[j], acc[i][j], 0, 0, 0);
                acc[i][j] = __builtin_amdgcn_mfma_f32_16x16x32_bf16(al2[i], bh[j],  acc[i][j], 0, 0, 0);
            }
        __syncthreads();
    }
    // epilogue: C/D layout col=lane&15, row=quad*4+reg (m89/m91)
    #pragma unroll
    for (int j = 0; j < 4; j++) {
        int n = n0 + wn + j * 16 + l16;
        if (n >= N) continue;
        float bv = bias ? bias[n] : 0.f;
        #pragma unroll
        for (int i = 0; i < 4; i++) {
            int mb = m0 + wm + i * 16 + quad * 4;
            #pragma unroll
            for (int r = 0; r < 4; r++) {
                float vv = acc[i][j][r] + bv;
                if (act == 1) vv = geluf(vv);
                Cmat[(long)(mb + r) * N + n] = vv;
            }
        }
    }
}

// ---- RoPE in-place on (B*KC, nh*64), positions = sel[row] ----
__global__ void k_rope(float* __restrict__ buf, const int* __restrict__ sel, int nh) {
    int tid = blockIdx.x * blockDim.x + threadIdx.x;
    int total = Bn * KCn * nh * 32;
    if (tid >= total) return;
    int d = tid & 31;
    int h = (tid >> 5) % nh;
    int r = tid / (32 * nh);
    int pos = sel[r];
    float theta = powf(10000.f, -(float)(2 * d) / 64.f);
    float ang = (float)pos * theta;
    float c = cosf(ang), s = sinf(ang);
    long base = (long)r * (nh * 64) + h * 64 + d;
    float x1 = buf[base], x2 = buf[base + 32];
    buf[base]      = x1 * c - x2 * s;
    buf[base + 32] = x2 * c + x1 * s;
}

// ---- fused attention: one block per (b,h,i): scores, softmax, PV ----
__global__ void k_attn(const float* __restrict__ q, const float* __restrict__ k,
                       const float* __restrict__ v, float* __restrict__ aout) {
    int blk = blockIdx.x;
    int i = blk & (KCn - 1);
    int h = (blk >> 8) & (NHn - 1);
    int b = blk >> 12;
    int hk = h >> 2;
    int tid = threadIdx.x;
    __shared__ float qs[HDn];
    __shared__ float probs[KCn];
    __shared__ float red[4];
    __shared__ float pr[4][HDn];
    if (tid < HDn) qs[tid] = q[((long)(b * KCn + i)) * (NHn * HDn) + h * HDn + tid];
    __syncthreads();
    int j = tid;
    const float* kr = k + ((long)(b * KCn + j)) * (NKVn * HDn) + hk * HDn;
    float dot = 0.f;
    #pragma unroll
    for (int d = 0; d < HDn; d++) dot += qs[d] * kr[d];
    float s = (j <= i) ? dot * 0.125f : -1e30f;
    float m = s;
    for (int o = 32; o > 0; o >>= 1) m = fmaxf(m, __shfl_down(m, o));
    int lane = tid & 63, w = tid >> 6;
    if (lane == 0) red[w] = m;
    __syncthreads();
    m = fmaxf(fmaxf(red[0], red[1]), fmaxf(red[2], red[3]));
    __syncthreads();
    float pe = expf(s - m);
    float z = pe;
    for (int o = 32; o > 0; o >>= 1) z += __shfl_down(z, o);
    if (lane == 0) red[w] = z;
    __syncthreads();
    z = red[0] + red[1] + red[2] + red[3];
    probs[tid] = pe / z;
    __syncthreads();
    int d = tid & 63, ch = tid >> 6;
    float part = 0.f;
    for (int jj = ch * 64; jj < ch * 64 + 64; jj++)
        part += probs[jj] * v[((long)(b * KCn + jj)) * (NKVn * HDn) + hk * HDn + d];
    pr[ch][d] = part;
    __syncthreads();
    if (tid < HDn) {
        float o = pr[0][tid] + pr[1][tid] + pr[2][tid] + pr[3][tid];
        aout[((long)(b * KCn + i)) * (NHn * HDn) + h * HDn + tid] = o;
    }
}

// ---- x2 = xs + ao; h2 = rmsnorm(x2, ln2). block per row ----
__global__ void k_add_ln2(const float* __restrict__ xs, const float* __restrict__ ao,
                          const float* __restrict__ w, float* __restrict__ h2) {
    int r = blockIdx.x;
    __shared__ float red[4];
    float v[4]; float ss = 0.f;
    #pragma unroll
    for (int j = 0; j < 4; j++) {
        int d = threadIdx.x + j * 256;
        float x = xs[(long)r * Dn + d] + ao[(long)r * Dn + d];
        v[j] = x; ss += x * x;
    }
    ss = blk_sum256(ss, red);
    float sc = 1.f / sqrtf(ss * (1.f / Dn) + 1e-6f);
    #pragma unroll
    for (int j = 0; j < 4; j++) {
        int d = threadIdx.x + j * 256;
        h2[(long)r * Dn + d] = v[j] * sc * w[d];
    }
}

// ---- gact = silu(gact)*uact ----
__global__ void k_silu_mul(float* __restrict__ gact, const float* __restrict__ uact, int n) {
    int i = blockIdx.x * blockDim.x + threadIdx.x;
    if (i < n) { float x = gact[i]; gact[i] = x * sigmf(x) * uact[i]; }
}

// ---- xp[b, sel[b,j], :] += g * (ao + ff). block per (b,j) ----
__global__ void k_scatter(float* __restrict__ xp, const float* __restrict__ ao,
                          const float* __restrict__ ff, const float* __restrict__ g,
                          const int* __restrict__ sel) {
    int r = blockIdx.x;
    int b = r / KCn;
    int p = sel[r];
    float gg = g[r];
    float* dst = xp + ((long)b * Pn + p) * Dn;
    #pragma unroll
    for (int j = 0; j < 4; j++) {
        int d = threadIdx.x + j * 256;
        dst[d] += gg * (ao[(long)r * Dn + d] + ff[(long)r * Dn + d]);
    }
}

// ---- win = sigmoid(hmlp @ w2 + b2). thread per (row, s) ----
__global__ void k_win(const float* __restrict__ hmlp, const float* __restrict__ w2,
                      const float* __restrict__ b2, float* __restrict__ win) {
    int tid = blockIdx.x * blockDim.x + threadIdx.x;
    if (tid >= Bn * Pn * Sn) return;
    int s = tid & 3; int r = tid >> 2;
    float acc = b2[s];
    const float* hr = hmlp + (long)r * 256;
    for (int i = 0; i < 256; i++) acc += hr[i] * w2[i * 4 + s];
    win[tid] = sigmf(acc);
}

// ---- y = rmsnorm(proj*win, dec_norm_w). block per row (8192 rows) ----
__global__ void k_dec_norm(const float* __restrict__ proj, const float* __restrict__ win,
                           const float* __restrict__ w, float* __restrict__ y) {
    int r = blockIdx.x;
    float wv = win[r];
    __shared__ float red[4];
    float v[4]; float ss = 0.f;
    #pragma unroll
    for (int j = 0; j < 4; j++) {
        int d = threadIdx.x + j * 256;
        float x = proj[(long)r * Dn + d] * wv;
        v[j] = x; ss += x * x;
    }
    ss = blk_sum256(ss, red);
    float sc = 1.f / sqrtf(ss * (1.f / Dn) + 1e-6f);
    #pragma unroll
    for (int j = 0; j < 4; j++) {
        int d = threadIdx.x + j * 256;
        y[(long)r * Dn + d] = v[j] * sc * w[d];
    }
}

extern "C" void kernel_launch(void* const* d_in, const int* in_sizes, int n_in,
                              void* d_out, int out_size, void* d_ws, size_t ws_size,
                              hipStream_t stream) {
    const int*   tokens     = (const int*)  d_in[0];
    const float* emb        = (const float*)d_in[1];
    const float* bp_w1      = (const float*)d_in[2];
    const float* bp_b1      = (const float*)d_in[3];
    const float* bp_w2      = (const float*)d_in[4];
    const float* bp_b2      = (const float*)d_in[5];
    const float* enc_norm_w = (const float*)d_in[6];
    const float* router_w   = (const float*)d_in[7];
    const float* ln1_w      = (const float*)d_in[8];
    const float* ln2_w      = (const float*)d_in[9];
    const float* q_w        = (const float*)d_in[10];
    const float* k_w        = (const float*)d_in[11];
    const float* v_w        = (const float*)d_in[12];
    const float* o_w        = (const float*)d_in[13];
    const float* gate_w     = (const float*)d_in[14];
    const float* up_w       = (const float*)d_in[15];
    const float* down_w     = (const float*)d_in[16];
    const float* dec_proj_w = (const float*)d_in[17];
    const float* dec_proj_b = (const float*)d_in[18];
    const float* dec_mlp_w1 = (const float*)d_in[19];
    const float* dec_mlp_b1 = (const float*)d_in[20];
    const float* dec_mlp_w2 = (const float*)d_in[21];
    const float* dec_mlp_b2 = (const float*)d_in[22];
    const float* dec_norm_w = (const float*)d_in[23];
    const float* head_w     = (const float*)d_in[24];
    float* out = (float*)d_out;

    float* W = (float*)d_ws;
    float* EW   = W + OFF_EW;
    float* cA   = W + OFF_CA;
    float* cB   = W + OFF_CB;
    float* cC   = W + OFF_CC;
    float* ent  = W + OFF_ENT;
    int*   idxb = (int*)(W + OFF_IDX);
    float* xp   = W + OFF_XP;
    float* rl   = W + OFF_RL;
    int*   sel  = (int*)(W + OFF_SEL);
    float* g    = W + OFF_G;
    float* scr  = W + SCR;
    float* xs   = scr + SC_XS;
    float* h    = scr + SC_H;
    float* qb   = scr + SC_Q;
    float* kb   = scr + SC_K;
    float* vb   = scr + SC_V;
    float* aout = scr + SC_AOUT;
    float* ao   = scr + SC_AO;
    float* h2   = scr + SC_H2;
    float* gact = scr + SC_GACT;
    float* uact = scr + SC_UACT;
    float* ffb  = scr + SC_FF;
    float* proj = scr + SC_PROJ;
    float* hmlp = scr + SC_HMLP;
    float* win  = scr + SC_WIN;
    float* y    = scr + SC_Y;

    // byte-patch encoder
    k_ew<<<dim3(96, 17), dim3(16, 16), 0, stream>>>(emb, bp_w1, EW);
    k_conv1<<<Bn * Tn / 4, 256, 0, stream>>>(tokens, EW, bp_b1, bp_w2, cA, cB, cC);
    k_patchstats<<<(Bn * Pn + 255) / 256, 256, 0, stream>>>(cA, cB, cC, bp_b2, ent, idxb);
    k_xp<<<Bn * Pn, 256, 0, stream>>>(tokens, idxb, emb, enc_norm_w, xp);

    for (int l = 0; l < Ln; l++) {
        k_router<<<Bn * Pn, 256, 0, stream>>>(xp, router_w + (long)l * Dn, ent, rl);
        k_topk<<<Bn, Pn, 0, stream>>>(rl, sel, g);
        k_gather_ln1<<<Bn * KCn, 256, 0, stream>>>(xp, sel, ln1_w + (long)l * Dn, xs, h);
        k_mfma<<<dim3(8, 8),  256, 0, stream>>>(h, q_w + (long)l * Dn * Dn, qb, nullptr, 1024, 1024, 1024, 0);
        k_mfma<<<dim3(2, 8),  256, 0, stream>>>(h, k_w + (long)l * Dn * 256, kb, nullptr, 1024, 256, 1024, 0);
        k_mfma<<<dim3(2, 8),  256, 0, stream>>>(h, v_w + (long)l * Dn * 256, vb, nullptr, 1024, 256, 1024, 0);
        k_rope<<<(Bn * KCn * NHn * 32 + 255) / 256, 256, 0, stream>>>(qb, sel, NHn);
        k_rope<<<(Bn * KCn * NKVn * 32 + 255) / 256, 256, 0, stream>>>(kb, sel, NKVn);
        k_attn<<<Bn * NHn * KCn, 256, 0, stream>>>(qb, kb, vb, aout);
        k_mfma<<<dim3(8, 8),  256, 0, stream>>>(aout, o_w + (long)l * Dn * Dn, ao, nullptr, 1024, 1024, 1024, 0);
        k_add_ln2<<<Bn * KCn, 256, 0, stream>>>(xs, ao, ln2_w + (long)l * Dn, h2);
        k_mfma<<<dim3(32, 8), 256, 0, stream>>>(h2, gate_w + (long)l * Dn * FFn, gact, nullptr, 1024, 4096, 1024, 0);
        k_mfma<<<dim3(32, 8), 256, 0, stream>>>(h2, up_w + (long)l * Dn * FFn, uact, nullptr, 1024, 4096, 1024, 0);
        k_silu_mul<<<(Bn * KCn * FFn + 255) / 256, 256, 0, stream>>>(gact, uact, Bn * KCn * FFn);
        k_mfma<<<dim3(8, 8),  256, 0, stream>>>(gact, down_w + (long)l * FFn * Dn, ffb, nullptr, 1024, 1024, 4096, 0);
        k_scatter<<<Bn * KCn, 256, 0, stream>>>(xp, ao, ffb, g, sel);
    }

    // decoder
    k_mfma<<<dim3(32, 16), 256, 0, stream>>>(xp, dec_proj_w, proj, dec_proj_b, 2048, 4096, 1024, 0);
    k_mfma<<<dim3(2, 16),  256, 0, stream>>>(xp, dec_mlp_w1, hmlp, dec_mlp_b1, 2048, 256, 1024, 1);
    k_win<<<(Bn * Pn * Sn + 255) / 256, 256, 0, stream>>>(hmlp, dec_mlp_w2, dec_mlp_b2, win);
    k_dec_norm<<<Bn * Pn * Sn, 256, 0, stream>>>(proj, win, dec_norm_w, y);
    k_mfma<<<dim3(3, 64),  256, 0, stream>>>(y, head_w, out, nullptr, 8192, 257, 1024, 0);
}

// Round 3
// 2688.177 us; speedup vs baseline: 2.1131x; 1.5782x over previous
//
#include <hip/hip_runtime.h>
#include <hip/hip_bf16.h>
#include <math.h>

// ---- model dims ----
constexpr int Bn  = 4;
constexpr int Tn  = 8192;
constexpr int Dn  = 1024;
constexpr int Pn  = 512;
constexpr int SEGn= 16;     // T/P
constexpr int Sn  = 4;
constexpr int Ln  = 4;
constexpr int NHn = 16;
constexpr int NKVn= 4;
constexpr int HDn = 64;
constexpr int FFn = 4096;
constexpr int KCn = 256;
constexpr int Vn  = 257;
constexpr int DHn = 512;    // conv hidden (D/2)

// ---- workspace layout (float elements). total = 19,908,096 floats = 76 MB ----
constexpr long OFF_EW  = 0;                       // 3*257*512 = 394752
constexpr long OFF_CA  = 394752;                  // B*T
constexpr long OFF_CB  = 427520;
constexpr long OFF_CC  = 460288;
constexpr long OFF_ENT = 493056;                  // B*P
constexpr long OFF_IDX = 495104;                  // B*P (int)
constexpr long OFF_XP  = 497152;                  // B*P*D = 2097152
constexpr long OFF_RL  = 2594304;                 // B*P
constexpr long OFF_SEL = 2596352;                 // B*KC (int)
constexpr long OFF_G   = 2597376;                 // B*KC
constexpr long SCR     = 2598400;
// layer-phase scratch (offsets relative to SCR):
constexpr long SC_XS   = 0;         // 1048576
constexpr long SC_H    = 1048576;   // 1048576
constexpr long SC_Q    = 2097152;   // 1048576
constexpr long SC_K    = 3145728;   // 262144
constexpr long SC_V    = 3407872;   // 262144
constexpr long SC_AOUT = 3670016;   // 1048576
constexpr long SC_AO   = 4718592;   // 1048576
constexpr long SC_H2   = 5767168;   // 1048576
constexpr long SC_GACT = 6815744;   // 4194304
constexpr long SC_UACT = 11010048;  // 4194304
constexpr long SC_FF   = 15204352;  // 1048576
// decoder-phase scratch (reuses layer region, after layers done):
constexpr long SC_PROJ = 0;         // 8388608
constexpr long SC_HMLP = 8388608;   // 524288
constexpr long SC_WIN  = 8912896;   // 8192
constexpr long SC_Y    = 8921088;   // 8388608

typedef __attribute__((ext_vector_type(8))) short short8;
typedef __attribute__((ext_vector_type(4))) float floatx4;

// ---- helpers ----
__device__ __forceinline__ float geluf(float x) {
    float x3 = x * x * x;
    return 0.5f * x * (1.f + tanhf(0.7978845608028654f * (x + 0.044715f * x3)));
}
__device__ __forceinline__ float sigmf(float x) { return 1.f / (1.f + expf(-x)); }

// fp32 -> bf16 hi/lo split (truncation; x ~= hi + lo, err ~2^-17 rel)
__device__ __forceinline__ void cvt_hilo(float x, unsigned short& h, unsigned short& l) {
    unsigned u = __float_as_uint(x);
    h = (unsigned short)(u >> 16);
    float r = x - __uint_as_float(u & 0xffff0000u);
    l = (unsigned short)(__float_as_uint(r) >> 16);
}

// block (256 threads) sum reduce; red must be __shared__ float[4]
__device__ __forceinline__ float blk_sum256(float v, float* red) {
    for (int o = 32; o > 0; o >>= 1) v += __shfl_down(v, o);
    int lane = threadIdx.x & 63, w = threadIdx.x >> 6;
    if (lane == 0) red[w] = v;
    __syncthreads();
    float r = red[0] + red[1] + red[2] + red[3];
    __syncthreads();
    return r;
}

// ---- zero buffer (graph-capture-safe memset replacement) ----
__global__ void k_zero(float* __restrict__ p, int n) {   // n multiple of 4
    int i = (blockIdx.x * blockDim.x + threadIdx.x) * 4;
    if (i < n) *(float4*)(p + i) = (float4){0.f, 0.f, 0.f, 0.f};
}

// ---- K0: EW[dk][v][o] = sum_i emb[v,i] * w1[o,i,dk] ----
__global__ void k_ew(const float* __restrict__ emb, const float* __restrict__ w1,
                     float* __restrict__ EW) {
    __shared__ float As[16][17];
    __shared__ float Ws[16][17];
    int c0 = blockIdx.x * 16, v0 = blockIdx.y * 16;
    int tx = threadIdx.x, ty = threadIdx.y;
    float acc = 0.f;
    int c = c0 + tx;
    int o = c / 3, dk = c - o * 3;
    for (int k0 = 0; k0 < Dn; k0 += 16) {
        int v = v0 + ty;
        As[ty][tx] = (v < Vn) ? emb[v * Dn + k0 + tx] : 0.f;
        Ws[ty][tx] = w1[o * 3072 + (k0 + ty) * 3 + dk];
        __syncthreads();
        #pragma unroll
        for (int kk = 0; kk < 16; kk++) acc += As[ty][kk] * Ws[kk][tx];
        __syncthreads();
    }
    int v = v0 + ty;
    if (v < Vn) EW[(long)dk * (Vn * DHn) + (long)v * DHn + o] = acc;
}

// ---- K1: per (b,t): h1 column via EW lookups + gelu, reduce to 3 dots with w2 ----
__global__ void k_conv1(const int* __restrict__ tok, const float* __restrict__ EW,
                        const float* __restrict__ b1, const float* __restrict__ w2,
                        float* __restrict__ cA, float* __restrict__ cB, float* __restrict__ cC) {
    int wave = threadIdx.x >> 6, lane = threadIdx.x & 63;
    int gidx = blockIdx.x * 4 + wave;     // b*T + t
    int b = gidx / Tn, t = gidx - b * Tn;
    int tk  = tok[b * Tn + t];
    int tkm = (t > 0)      ? tok[b * Tn + t - 1] : -1;
    int tkp = (t < Tn - 1) ? tok[b * Tn + t + 1] : -1;
    const float* E0 = EW;
    const float* E1 = EW + (long)Vn * DHn;
    const float* E2 = EW + 2L * Vn * DHn;
    float a0 = 0.f, a1 = 0.f, a2 = 0.f;
    #pragma unroll
    for (int u = 0; u < DHn / 64; u++) {
        int o = lane + u * 64;
        float s = b1[o] + E1[tk * DHn + o];
        if (tkm >= 0) s += E0[tkm * DHn + o];
        if (tkp >= 0) s += E2[tkp * DHn + o];
        float hg = geluf(s);
        a0 += hg * w2[o * 3 + 0];
        a1 += hg * w2[o * 3 + 1];
        a2 += hg * w2[o * 3 + 2];
    }
    for (int o = 32; o > 0; o >>= 1) {
        a0 += __shfl_down(a0, o); a1 += __shfl_down(a1, o); a2 += __shfl_down(a2, o);
    }
    if (lane == 0) { cA[gidx] = a0; cB[gidx] = a1; cC[gidx] = a2; }
}

// ---- K2: lg per token -> per-patch softmax -> ent, idx ----
__global__ void k_patchstats(const float* __restrict__ cA, const float* __restrict__ cB,
                             const float* __restrict__ cC, const float* __restrict__ b2,
                             float* __restrict__ ent_out, int* __restrict__ idx_out) {
    int pid = blockIdx.x * blockDim.x + threadIdx.x;   // b*P + p
    if (pid >= Bn * Pn) return;
    int b = pid / Pn, p = pid - b * Pn;
    float lgv[SEGn];
    float m = -3.4e38f;
    for (int s = 0; s < SEGn; s++) {
        int t = p * SEGn + s;
        float v = b2[0] + cB[b * Tn + t];
        if (t > 0)      v += cA[b * Tn + t - 1];
        if (t < Tn - 1) v += cC[b * Tn + t + 1];
        lgv[s] = v; m = fmaxf(m, v);
    }
    float Z = 0.f;
    for (int s = 0; s < SEGn; s++) { lgv[s] = expf(lgv[s] - m); Z += lgv[s]; }
    float inv = 1.f / Z;
    float bp = 0.f, en = 0.f;
    for (int s = 0; s < SEGn; s++) {
        float w = lgv[s] * inv;
        bp += w * (float)(p * SEGn + s);
        en -= w * logf(fmaxf(w, 1e-8f));
    }
    en *= (1.f / 2.772588722239781f);   // / ln(16)
    ent_out[pid] = en;
    int ix = (int)bp;
    ix = ix < 0 ? 0 : (ix > Tn - 1 ? Tn - 1 : ix);
    idx_out[pid] = ix;
}

// ---- K3: xp[b,p,:] = rmsnorm(emb[tok[b, idx[b,p]]], enc_norm_w). block per row ----
__global__ void k_xp(const int* __restrict__ tok, const int* __restrict__ idx,
                     const float* __restrict__ emb, const float* __restrict__ nw,
                     float* __restrict__ xp) {
    int pid = blockIdx.x;
    int b = pid / Pn;
    int tk = tok[b * Tn + idx[pid]];
    const float* row = emb + (long)tk * Dn;
    __shared__ float red[4];
    float v[4]; float ss = 0.f;
    #pragma unroll
    for (int j = 0; j < 4; j++) { v[j] = row[threadIdx.x + j * 256]; ss += v[j] * v[j]; }
    ss = blk_sum256(ss, red);
    float sc = 1.f / sqrtf(ss * (1.f / Dn) + 1e-6f);
    #pragma unroll
    for (int j = 0; j < 4; j++) {
        int d = threadIdx.x + j * 256;
        xp[(long)pid * Dn + d] = v[j] * sc * nw[d];
    }
}

// ---- K4: rl[b,p] = xp[b,p,:]·rw + ent. block per row ----
__global__ void k_router(const float* __restrict__ xp, const float* __restrict__ rw,
                         const float* __restrict__ ent, float* __restrict__ rl) {
    int pid = blockIdx.x;
    const float* xr = xp + (long)pid * Dn;
    __shared__ float red[4];
    float s = 0.f;
    #pragma unroll
    for (int j = 0; j < 4; j++) { int d = threadIdx.x + j * 256; s += xr[d] * rw[d]; }
    s = blk_sum256(s, red);
    if (threadIdx.x == 0) rl[pid] = s + ent[pid];
}

// ---- K5: exact top-k (KC of P) with jax tie semantics, output ascending by index ----
__global__ void k_topk(const float* __restrict__ rl, int* __restrict__ sel, float* __restrict__ g) {
    int b = blockIdx.x, p = threadIdx.x;
    __shared__ float vals[Pn];
    __shared__ int flag[Pn];
    float v = rl[b * Pn + p];
    vals[p] = v;
    __syncthreads();
    int rank = 0;
    for (int q = 0; q < Pn; q++) {
        float vq = vals[q];
        rank += (vq > v || (vq == v && q < p)) ? 1 : 0;
    }
    int selected = rank < KCn ? 1 : 0;
    flag[p] = selected;
    __syncthreads();
    if (selected) {
        int pos = 0;
        for (int q = 0; q < p; q++) pos += flag[q];
        sel[b * KCn + pos] = p;
        g[b * KCn + pos] = sigmf(v);
    }
}

// ---- K6: gather xs = xp[b, sel], h = rmsnorm(xs, ln1). block per (b,j) ----
__global__ void k_gather_ln1(const float* __restrict__ xp, const int* __restrict__ sel,
                             const float* __restrict__ w, float* __restrict__ xs,
                             float* __restrict__ h) {
    int r = blockIdx.x;            // b*KC + j
    int b = r / KCn;
    int p = sel[r];
    const float* src = xp + ((long)b * Pn + p) * Dn;
    __shared__ float red[4];
    float v[4]; float ss = 0.f;
    #pragma unroll
    for (int j = 0; j < 4; j++) { v[j] = src[threadIdx.x + j * 256]; ss += v[j] * v[j]; }
    ss = blk_sum256(ss, red);
    float sc = 1.f / sqrtf(ss * (1.f / Dn) + 1e-6f);
    #pragma unroll
    for (int j = 0; j < 4; j++) {
        int d = threadIdx.x + j * 256;
        xs[(long)r * Dn + d] = v[j];
        h[(long)r * Dn + d] = v[j] * sc * w[d];
    }
}

// ---- MFMA GEMM, fp32-accurate via bf16 hi/lo x3, double-buffered + split-K ----
// C[M,N] = A[M,K] @ W[K,N] (+bias). grid (ceil(N/128), M/128, splitK), block 256.
// splitK>1: epilogue atomicAdd (C must be pre-zeroed); bias added by chunk 0 only.
// M%128==0, (K/splitK)%32==0. N arbitrary.
constexpr int RS = 40;  // LDS row stride (bf16): frag ds_read_b128 lands 2-way bank alias (free, m136)
__global__ __launch_bounds__(256) void k_mfma(const float* __restrict__ A, const float* __restrict__ Wm,
                       float* __restrict__ Cmat, const float* __restrict__ bias,
                       int M, int N, int K, int splitK) {
    __shared__ alignas(16) unsigned short Ah[2][128 * RS], Al[2][128 * RS],
                                          Bh[2][128 * RS], Bl[2][128 * RS];
    int tid = threadIdx.x;
    int m0 = blockIdx.y * 128, n0 = blockIdx.x * 128;
    int kchunk = blockIdx.z;
    int Kc = K / splitK;
    int kbase = kchunk * Kc;
    int KT = Kc >> 5;
    int lane = tid & 63, wid = tid >> 6;
    int wm = (wid & 1) * 64, wn = (wid >> 1) * 64;
    int quad = lane >> 4, l16 = lane & 15;
    floatx4 acc[4][4];
    #pragma unroll
    for (int i = 0; i < 4; i++)
        #pragma unroll
        for (int j = 0; j < 4; j++) acc[i][j] = (floatx4){0.f, 0.f, 0.f, 0.f};

    int arow = tid >> 3, ak4 = (tid & 7) * 4;   // A: row = arow+32*r4, k-cols ak4..ak4+3
    int bkb = (tid >> 5) * 4, bn = tid & 31;    // B: k-rows bkb..bkb+3, n = bn+32*j (stride-1 coalesced)

    float4 av[4];
    float  bv[4][4];

    auto load_tile = [&](int k0) {
        #pragma unroll
        for (int r4 = 0; r4 < 4; r4++)
            av[r4] = *(const float4*)(A + (long)(m0 + arow + r4 * 32) * K + k0 + ak4);
        #pragma unroll
        for (int i = 0; i < 4; i++)
            #pragma unroll
            for (int j = 0; j < 4; j++) {
                int n = n0 + bn + 32 * j;
                bv[i][j] = (n < N) ? Wm[(long)(k0 + bkb + i) * N + n] : 0.f;
            }
    };
    auto stage_tile = [&](int buf) {
        #pragma unroll
        for (int r4 = 0; r4 < 4; r4++) {
            int row = arow + r4 * 32;
            unsigned short h0, h1, h2, h3, l0, l1, l2, l3;
            cvt_hilo(av[r4].x, h0, l0); cvt_hilo(av[r4].y, h1, l1);
            cvt_hilo(av[r4].z, h2, l2); cvt_hilo(av[r4].w, h3, l3);
            *(ushort4*)&Ah[buf][row * RS + ak4] = make_ushort4(h0, h1, h2, h3);
            *(ushort4*)&Al[buf][row * RS + ak4] = make_ushort4(l0, l1, l2, l3);
        }
        #pragma unroll
        for (int j = 0; j < 4; j++) {
            int n = bn + 32 * j;
            unsigned short h[4], l[4];
            #pragma unroll
            for (int i = 0; i < 4; i++) cvt_hilo(bv[i][j], h[i], l[i]);
            *(ushort4*)&Bh[buf][n * RS + bkb] = make_ushort4(h[0], h[1], h[2], h[3]);
            *(ushort4*)&Bl[buf][n * RS + bkb] = make_ushort4(l[0], l[1], l[2], l[3]);
        }
    };

    load_tile(kbase);
    stage_tile(0);
    __syncthreads();

    for (int ks = 0; ks < KT; ks++) {
        int cur = ks & 1;
        if (ks + 1 < KT) load_tile(kbase + (ks + 1) * 32);   // prefetch (vmcnt waits sink into stage)
        short8 ah[4], al2[4], bh[4], bl2[4];
        #pragma unroll
        for (int i = 0; i < 4; i++) {
            int r = wm + i * 16 + l16;
            ah[i]  = *(const short8*)&Ah[cur][r * RS + quad * 8];
            al2[i] = *(const short8*)&Al[cur][r * RS + quad * 8];
        }
        #pragma unroll
        for (int j = 0; j < 4; j++) {
            int c = wn + j * 16 + l16;
            bh[j]  = *(const short8*)&Bh[cur][c * RS + quad * 8];
            bl2[j] = *(const short8*)&Bl[cur][c * RS + quad * 8];
        }
        #pragma unroll
        for (int i = 0; i < 4; i++)
            #pragma unroll
            for (int j = 0; j < 4; j++) {
                acc[i][j] = __builtin_amdgcn_mfma_f32_16x16x32_bf16(ah[i],  bh[j],  acc[i][j], 0, 0, 0);
                acc[i][j] = __builtin_amdgcn_mfma_f32_16x16x32_bf16(ah[i],  bl2[j], acc[i][j], 0, 0, 0);
                acc[i][j] = __builtin_amdgcn_mfma_f32_16x16x32_bf16(al2[i], bh[j],  acc[i][j], 0, 0, 0);
            }
        if (ks + 1 < KT) stage_tile(cur ^ 1);
        __syncthreads();
    }

    // epilogue: C/D layout col=lane&15, row=quad*4+reg (m89/m91)
    #pragma unroll
    for (int j = 0; j < 4; j++) {
        int n = n0 + wn + j * 16 + l16;
        if (n >= N) continue;
        float bvx = (bias && kchunk == 0) ? bias[n] : 0.f;
        #pragma unroll
        for (int i = 0; i < 4; i++) {
            int mb = m0 + wm + i * 16 + quad * 4;
            #pragma unroll
            for (int r = 0; r < 4; r++) {
                float vv = acc[i][j][r] + bvx;
                if (splitK > 1) atomicAdd(&Cmat[(long)(mb + r) * N + n], vv);
                else            Cmat[(long)(mb + r) * N + n] = vv;
            }
        }
    }
}

// ---- RoPE in-place on (B*KC, nh*64), positions = sel[row] ----
__global__ void k_rope(float* __restrict__ buf, const int* __restrict__ sel, int nh) {
    int tid = blockIdx.x * blockDim.x + threadIdx.x;
    int total = Bn * KCn * nh * 32;
    if (tid >= total) return;
    int d = tid & 31;
    int h = (tid >> 5) % nh;
    int r = tid / (32 * nh);
    int pos = sel[r];
    float theta = powf(10000.f, -(float)(2 * d) / 64.f);
    float ang = (float)pos * theta;
    float c = cosf(ang), s = sinf(ang);
    long base = (long)r * (nh * 64) + h * 64 + d;
    float x1 = buf[base], x2 = buf[base + 32];
    buf[base]      = x1 * c - x2 * s;
    buf[base + 32] = x2 * c + x1 * s;
}

// ---- fused attention: one block per (b,h,i): scores, softmax, PV ----
__global__ void k_attn(const float* __restrict__ q, const float* __restrict__ k,
                       const float* __restrict__ v, float* __restrict__ aout) {
    int blk = blockIdx.x;
    int i = blk & (KCn - 1);
    int h = (blk >> 8) & (NHn - 1);
    int b = blk >> 12;
    int hk = h >> 2;
    int tid = threadIdx.x;
    __shared__ float qs[HDn];
    __shared__ float probs[KCn];
    __shared__ float red[4];
    __shared__ float pr[4][HDn];
    if (tid < HDn) qs[tid] = q[((long)(b * KCn + i)) * (NHn * HDn) + h * HDn + tid];
    __syncthreads();
    int j = tid;
    const float* kr = k + ((long)(b * KCn + j)) * (NKVn * HDn) + hk * HDn;
    float dot = 0.f;
    #pragma unroll
    for (int d = 0; d < HDn; d++) dot += qs[d] * kr[d];
    float s = (j <= i) ? dot * 0.125f : -1e30f;
    float m = s;
    for (int o = 32; o > 0; o >>= 1) m = fmaxf(m, __shfl_down(m, o));
    int lane = tid & 63, w = tid >> 6;
    if (lane == 0) red[w] = m;
    __syncthreads();
    m = fmaxf(fmaxf(red[0], red[1]), fmaxf(red[2], red[3]));
    __syncthreads();
    float pe = expf(s - m);
    float z = pe;
    for (int o = 32; o > 0; o >>= 1) z += __shfl_down(z, o);
    if (lane == 0) red[w] = z;
    __syncthreads();
    z = red[0] + red[1] + red[2] + red[3];
    probs[tid] = pe / z;
    __syncthreads();
    int d = tid & 63, ch = tid >> 6;
    float part = 0.f;
    for (int jj = ch * 64; jj < ch * 64 + 64; jj++)
        part += probs[jj] * v[((long)(b * KCn + jj)) * (NKVn * HDn) + hk * HDn + d];
    pr[ch][d] = part;
    __syncthreads();
    if (tid < HDn) {
        float o = pr[0][tid] + pr[1][tid] + pr[2][tid] + pr[3][tid];
        aout[((long)(b * KCn + i)) * (NHn * HDn) + h * HDn + tid] = o;
    }
}

// ---- x2 = xs + ao; h2 = rmsnorm(x2, ln2). block per row ----
__global__ void k_add_ln2(const float* __restrict__ xs, const float* __restrict__ ao,
                          const float* __restrict__ w, float* __restrict__ h2) {
    int r = blockIdx.x;
    __shared__ float red[4];
    float v[4]; float ss = 0.f;
    #pragma unroll
    for (int j = 0; j < 4; j++) {
        int d = threadIdx.x + j * 256;
        float x = xs[(long)r * Dn + d] + ao[(long)r * Dn + d];
        v[j] = x; ss += x * x;
    }
    ss = blk_sum256(ss, red);
    float sc = 1.f / sqrtf(ss * (1.f / Dn) + 1e-6f);
    #pragma unroll
    for (int j = 0; j < 4; j++) {
        int d = threadIdx.x + j * 256;
        h2[(long)r * Dn + d] = v[j] * sc * w[d];
    }
}

// ---- gact = silu(gact)*uact ----
__global__ void k_silu_mul(float* __restrict__ gact, const float* __restrict__ uact, int n) {
    int i = blockIdx.x * blockDim.x + threadIdx.x;
    if (i < n) { float x = gact[i]; gact[i] = x * sigmf(x) * uact[i]; }
}

// ---- xp[b, sel[b,j], :] += g * (ao + ff). block per (b,j) ----
__global__ void k_scatter(float* __restrict__ xp, const float* __restrict__ ao,
                          const float* __restrict__ ff, const float* __restrict__ g,
                          const int* __restrict__ sel) {
    int r = blockIdx.x;
    int b = r / KCn;
    int p = sel[r];
    float gg = g[r];
    float* dst = xp + ((long)b * Pn + p) * Dn;
    #pragma unroll
    for (int j = 0; j < 4; j++) {
        int d = threadIdx.x + j * 256;
        dst[d] += gg * (ao[(long)r * Dn + d] + ff[(long)r * Dn + d]);
    }
}

// ---- win = sigmoid(gelu(hmlp) @ w2 + b2). gelu applied here (splitK GEMM can't fuse act) ----
__global__ void k_win(const float* __restrict__ hmlp, const float* __restrict__ w2,
                      const float* __restrict__ b2, float* __restrict__ win) {
    int tid = blockIdx.x * blockDim.x + threadIdx.x;
    if (tid >= Bn * Pn * Sn) return;
    int s = tid & 3; int r = tid >> 2;
    float acc = b2[s];
    const float* hr = hmlp + (long)r * 256;
    for (int i = 0; i < 256; i++) acc += geluf(hr[i]) * w2[i * 4 + s];
    win[tid] = sigmf(acc);
}

// ---- y = rmsnorm(proj*win, dec_norm_w). block per row (8192 rows) ----
__global__ void k_dec_norm(const float* __restrict__ proj, const float* __restrict__ win,
                           const float* __restrict__ w, float* __restrict__ y) {
    int r = blockIdx.x;
    float wv = win[r];
    __shared__ float red[4];
    float v[4]; float ss = 0.f;
    #pragma unroll
    for (int j = 0; j < 4; j++) {
        int d = threadIdx.x + j * 256;
        float x = proj[(long)r * Dn + d] * wv;
        v[j] = x; ss += x * x;
    }
    ss = blk_sum256(ss, red);
    float sc = 1.f / sqrtf(ss * (1.f / Dn) + 1e-6f);
    #pragma unroll
    for (int j = 0; j < 4; j++) {
        int d = threadIdx.x + j * 256;
        y[(long)r * Dn + d] = v[j] * sc * w[d];
    }
}

extern "C" void kernel_launch(void* const* d_in, const int* in_sizes, int n_in,
                              void* d_out, int out_size, void* d_ws, size_t ws_size,
                              hipStream_t stream) {
    const int*   tokens     = (const int*)  d_in[0];
    const float* emb        = (const float*)d_in[1];
    const float* bp_w1      = (const float*)d_in[2];
    const float* bp_b1      = (const float*)d_in[3];
    const float* bp_w2      = (const float*)d_in[4];
    const float* bp_b2      = (const float*)d_in[5];
    const float* enc_norm_w = (const float*)d_in[6];
    const float* router_w   = (const float*)d_in[7];
    const float* ln1_w      = (const float*)d_in[8];
    const float* ln2_w      = (const float*)d_in[9];
    const float* q_w        = (const float*)d_in[10];
    const float* k_w        = (const float*)d_in[11];
    const float* v_w        = (const float*)d_in[12];
    const float* o_w        = (const float*)d_in[13];
    const float* gate_w     = (const float*)d_in[14];
    const float* up_w       = (const float*)d_in[15];
    const float* down_w     = (const float*)d_in[16];
    const float* dec_proj_w = (const float*)d_in[17];
    const float* dec_proj_b = (const float*)d_in[18];
    const float* dec_mlp_w1 = (const float*)d_in[19];
    const float* dec_mlp_b1 = (const float*)d_in[20];
    const float* dec_mlp_w2 = (const float*)d_in[21];
    const float* dec_mlp_b2 = (const float*)d_in[22];
    const float* dec_norm_w = (const float*)d_in[23];
    const float* head_w     = (const float*)d_in[24];
    float* out = (float*)d_out;

    float* W = (float*)d_ws;
    float* EW   = W + OFF_EW;
    float* cA   = W + OFF_CA;
    float* cB   = W + OFF_CB;
    float* cC   = W + OFF_CC;
    float* ent  = W + OFF_ENT;
    int*   idxb = (int*)(W + OFF_IDX);
    float* xp   = W + OFF_XP;
    float* rl   = W + OFF_RL;
    int*   sel  = (int*)(W + OFF_SEL);
    float* g    = W + OFF_G;
    float* scr  = W + SCR;
    float* xs   = scr + SC_XS;
    float* h    = scr + SC_H;
    float* qb   = scr + SC_Q;
    float* kb   = scr + SC_K;
    float* vb   = scr + SC_V;
    float* aout = scr + SC_AOUT;
    float* ao   = scr + SC_AO;
    float* h2   = scr + SC_H2;
    float* gact = scr + SC_GACT;
    float* uact = scr + SC_UACT;
    float* ffb  = scr + SC_FF;
    float* proj = scr + SC_PROJ;
    float* hmlp = scr + SC_HMLP;
    float* win  = scr + SC_WIN;
    float* y    = scr + SC_Y;

    // byte-patch encoder
    k_ew<<<dim3(96, 17), dim3(16, 16), 0, stream>>>(emb, bp_w1, EW);
    k_conv1<<<Bn * Tn / 4, 256, 0, stream>>>(tokens, EW, bp_b1, bp_w2, cA, cB, cC);
    k_patchstats<<<(Bn * Pn + 255) / 256, 256, 0, stream>>>(cA, cB, cC, bp_b2, ent, idxb);
    k_xp<<<Bn * Pn, 256, 0, stream>>>(tokens, idxb, emb, enc_norm_w, xp);

    for (int l = 0; l < Ln; l++) {
        k_router<<<Bn * Pn, 256, 0, stream>>>(xp, router_w + (long)l * Dn, ent, rl);
        k_topk<<<Bn, Pn, 0, stream>>>(rl, sel, g);
        k_gather_ln1<<<Bn * KCn, 256, 0, stream>>>(xp, sel, ln1_w + (long)l * Dn, xs, h);
        // zero atomic-accumulated GEMM outputs (qb..vb contiguous 1.5M floats)
        k_zero<<<(1572864 / 4 + 255) / 256, 256, 0, stream>>>(qb, 1572864);
        k_zero<<<(1048576 / 4 + 255) / 256, 256, 0, stream>>>(ao, 1048576);
        k_zero<<<(1048576 / 4 + 255) / 256, 256, 0, stream>>>(ffb, 1048576);
        k_mfma<<<dim3(8, 8, 4),  256, 0, stream>>>(h, q_w + (long)l * Dn * Dn, qb, nullptr, 1024, 1024, 1024, 4);
        k_mfma<<<dim3(2, 8, 8),  256, 0, stream>>>(h, k_w + (long)l * Dn * 256, kb, nullptr, 1024, 256, 1024, 8);
        k_mfma<<<dim3(2, 8, 8),  256, 0, stream>>>(h, v_w + (long)l * Dn * 256, vb, nullptr, 1024, 256, 1024, 8);
        k_rope<<<(Bn * KCn * NHn * 32 + 255) / 256, 256, 0, stream>>>(qb, sel, NHn);
        k_rope<<<(Bn * KCn * NKVn * 32 + 255) / 256, 256, 0, stream>>>(kb, sel, NKVn);
        k_attn<<<Bn * NHn * KCn, 256, 0, stream>>>(qb, kb, vb, aout);
        k_mfma<<<dim3(8, 8, 4),  256, 0, stream>>>(aout, o_w + (long)l * Dn * Dn, ao, nullptr, 1024, 1024, 1024, 4);
        k_add_ln2<<<Bn * KCn, 256, 0, stream>>>(xs, ao, ln2_w + (long)l * Dn, h2);
        k_mfma<<<dim3(32, 8, 1), 256, 0, stream>>>(h2, gate_w + (long)l * Dn * FFn, gact, nullptr, 1024, 4096, 1024, 1);
        k_mfma<<<dim3(32, 8, 1), 256, 0, stream>>>(h2, up_w + (long)l * Dn * FFn, uact, nullptr, 1024, 4096, 1024, 1);
        k_silu_mul<<<(Bn * KCn * FFn + 255) / 256, 256, 0, stream>>>(gact, uact, Bn * KCn * FFn);
        k_mfma<<<dim3(8, 8, 4),  256, 0, stream>>>(gact, down_w + (long)l * FFn * Dn, ffb, nullptr, 1024, 1024, 4096, 4);
        k_scatter<<<Bn * KCn, 256, 0, stream>>>(xp, ao, ffb, g, sel);
    }

    // decoder
    k_mfma<<<dim3(32, 16, 1), 256, 0, stream>>>(xp, dec_proj_w, proj, dec_proj_b, 2048, 4096, 1024, 1);
    k_zero<<<(524288 / 4 + 255) / 256, 256, 0, stream>>>(hmlp, 524288);
    k_mfma<<<dim3(2, 16, 4),  256, 0, stream>>>(xp, dec_mlp_w1, hmlp, dec_mlp_b1, 2048, 256, 1024, 4);
    k_win<<<(Bn * Pn * Sn + 255) / 256, 256, 0, stream>>>(hmlp, dec_mlp_w2, dec_mlp_b2, win);
    k_dec_norm<<<Bn * Pn * Sn, 256, 0, stream>>>(proj, win, dec_norm_w, y);
    k_mfma<<<dim3(3, 64, 1),  256, 0, stream>>>(y, head_w, out, nullptr, 8192, 257, 1024, 1);
}

// Round 4
// 2104.074 us; speedup vs baseline: 2.6997x; 1.2776x over previous
//
#include <hip/hip_runtime.h>
#include <hip/hip_bf16.h>
#include <math.h>

// ---- model dims ----
constexpr int Bn  = 4;
constexpr int Tn  = 8192;
constexpr int Dn  = 1024;
constexpr int Pn  = 512;
constexpr int SEGn= 16;     // T/P
constexpr int Sn  = 4;
constexpr int Ln  = 4;
constexpr int NHn = 16;
constexpr int NKVn= 4;
constexpr int HDn = 64;
constexpr int FFn = 4096;
constexpr int KCn = 256;
constexpr int Vn  = 257;
constexpr int DHn = 512;    // conv hidden (D/2)

// ---- workspace layout (float elements). total = 19,908,096 floats = 76 MB ----
constexpr long OFF_EW  = 0;                       // 3*257*512 = 394752
constexpr long OFF_CA  = 394752;                  // B*T
constexpr long OFF_CB  = 427520;
constexpr long OFF_CC  = 460288;
constexpr long OFF_ENT = 493056;                  // B*P
constexpr long OFF_IDX = 495104;                  // B*P (int)
constexpr long OFF_XP  = 497152;                  // B*P*D = 2097152
constexpr long OFF_RL  = 2594304;                 // B*P
constexpr long OFF_SEL = 2596352;                 // B*KC (int)
constexpr long OFF_G   = 2597376;                 // B*KC
constexpr long SCR     = 2598400;
// layer-phase scratch (offsets relative to SCR):
constexpr long SC_XS   = 0;         // 1048576
constexpr long SC_H    = 1048576;   // 1048576
constexpr long SC_Q    = 2097152;   // 1048576
constexpr long SC_K    = 3145728;   // 262144
constexpr long SC_V    = 3407872;   // 262144
constexpr long SC_AOUT = 3670016;   // 1048576
constexpr long SC_AO   = 4718592;   // 1048576
constexpr long SC_H2   = 5767168;   // 1048576
constexpr long SC_GACT = 6815744;   // 4194304
constexpr long SC_UACT = 11010048;  // 4194304
constexpr long SC_FF   = 15204352;  // 1048576
// decoder-phase scratch (reuses layer region, after layers done):
constexpr long SC_PROJ = 0;         // 8388608
constexpr long SC_HMLP = 8388608;   // 524288
constexpr long SC_WIN  = 8912896;   // 8192
constexpr long SC_Y    = 8921088;   // 8388608

typedef __attribute__((ext_vector_type(8))) short short8;
typedef __attribute__((ext_vector_type(4))) float floatx4;

// ---- helpers ----
__device__ __forceinline__ float geluf(float x) {
    float x3 = x * x * x;
    return 0.5f * x * (1.f + tanhf(0.7978845608028654f * (x + 0.044715f * x3)));
}
__device__ __forceinline__ float sigmf(float x) { return 1.f / (1.f + expf(-x)); }

// fp32 -> bf16 hi/lo split (truncation; x ~= hi + lo, err ~2^-17 rel)
__device__ __forceinline__ void cvt_hilo(float x, unsigned short& h, unsigned short& l) {
    unsigned u = __float_as_uint(x);
    h = (unsigned short)(u >> 16);
    float r = x - __uint_as_float(u & 0xffff0000u);
    l = (unsigned short)(__float_as_uint(r) >> 16);
}

// block (256 threads) sum reduce; red must be __shared__ float[4]
__device__ __forceinline__ float blk_sum256(float v, float* red) {
    for (int o = 32; o > 0; o >>= 1) v += __shfl_down(v, o);
    int lane = threadIdx.x & 63, w = threadIdx.x >> 6;
    if (lane == 0) red[w] = v;
    __syncthreads();
    float r = red[0] + red[1] + red[2] + red[3];
    __syncthreads();
    return r;
}

// ---- zero buffer (graph-capture-safe memset replacement) ----
__global__ void k_zero(float* __restrict__ p, int n) {   // n multiple of 4
    int i = (blockIdx.x * blockDim.x + threadIdx.x) * 4;
    if (i < n) *(float4*)(p + i) = (float4){0.f, 0.f, 0.f, 0.f};
}

// ---- K0: EW[dk][v][o] = sum_i emb[v,i] * w1[o,i,dk] ----
__global__ void k_ew(const float* __restrict__ emb, const float* __restrict__ w1,
                     float* __restrict__ EW) {
    __shared__ float As[16][17];
    __shared__ float Ws[16][17];
    int c0 = blockIdx.x * 16, v0 = blockIdx.y * 16;
    int tx = threadIdx.x, ty = threadIdx.y;
    float acc = 0.f;
    int c = c0 + tx;
    int o = c / 3, dk = c - o * 3;
    for (int k0 = 0; k0 < Dn; k0 += 16) {
        int v = v0 + ty;
        As[ty][tx] = (v < Vn) ? emb[v * Dn + k0 + tx] : 0.f;
        Ws[ty][tx] = w1[o * 3072 + (k0 + ty) * 3 + dk];
        __syncthreads();
        #pragma unroll
        for (int kk = 0; kk < 16; kk++) acc += As[ty][kk] * Ws[kk][tx];
        __syncthreads();
    }
    int v = v0 + ty;
    if (v < Vn) EW[(long)dk * (Vn * DHn) + (long)v * DHn + o] = acc;
}

// ---- K1: per (b,t): h1 column via EW lookups + gelu, reduce to 3 dots with w2 ----
__global__ void k_conv1(const int* __restrict__ tok, const float* __restrict__ EW,
                        const float* __restrict__ b1, const float* __restrict__ w2,
                        float* __restrict__ cA, float* __restrict__ cB, float* __restrict__ cC) {
    int wave = threadIdx.x >> 6, lane = threadIdx.x & 63;
    int gidx = blockIdx.x * 4 + wave;     // b*T + t
    int b = gidx / Tn, t = gidx - b * Tn;
    int tk  = tok[b * Tn + t];
    int tkm = (t > 0)      ? tok[b * Tn + t - 1] : -1;
    int tkp = (t < Tn - 1) ? tok[b * Tn + t + 1] : -1;
    const float* E0 = EW;
    const float* E1 = EW + (long)Vn * DHn;
    const float* E2 = EW + 2L * Vn * DHn;
    float a0 = 0.f, a1 = 0.f, a2 = 0.f;
    #pragma unroll
    for (int u = 0; u < DHn / 64; u++) {
        int o = lane + u * 64;
        float s = b1[o] + E1[tk * DHn + o];
        if (tkm >= 0) s += E0[tkm * DHn + o];
        if (tkp >= 0) s += E2[tkp * DHn + o];
        float hg = geluf(s);
        a0 += hg * w2[o * 3 + 0];
        a1 += hg * w2[o * 3 + 1];
        a2 += hg * w2[o * 3 + 2];
    }
    for (int o = 32; o > 0; o >>= 1) {
        a0 += __shfl_down(a0, o); a1 += __shfl_down(a1, o); a2 += __shfl_down(a2, o);
    }
    if (lane == 0) { cA[gidx] = a0; cB[gidx] = a1; cC[gidx] = a2; }
}

// ---- K2: lg per token -> per-patch softmax -> ent, idx ----
__global__ void k_patchstats(const float* __restrict__ cA, const float* __restrict__ cB,
                             const float* __restrict__ cC, const float* __restrict__ b2,
                             float* __restrict__ ent_out, int* __restrict__ idx_out) {
    int pid = blockIdx.x * blockDim.x + threadIdx.x;   // b*P + p
    if (pid >= Bn * Pn) return;
    int b = pid / Pn, p = pid - b * Pn;
    float lgv[SEGn];
    float m = -3.4e38f;
    for (int s = 0; s < SEGn; s++) {
        int t = p * SEGn + s;
        float v = b2[0] + cB[b * Tn + t];
        if (t > 0)      v += cA[b * Tn + t - 1];
        if (t < Tn - 1) v += cC[b * Tn + t + 1];
        lgv[s] = v; m = fmaxf(m, v);
    }
    float Z = 0.f;
    for (int s = 0; s < SEGn; s++) { lgv[s] = expf(lgv[s] - m); Z += lgv[s]; }
    float inv = 1.f / Z;
    float bp = 0.f, en = 0.f;
    for (int s = 0; s < SEGn; s++) {
        float w = lgv[s] * inv;
        bp += w * (float)(p * SEGn + s);
        en -= w * logf(fmaxf(w, 1e-8f));
    }
    en *= (1.f / 2.772588722239781f);   // / ln(16)
    ent_out[pid] = en;
    int ix = (int)bp;
    ix = ix < 0 ? 0 : (ix > Tn - 1 ? Tn - 1 : ix);
    idx_out[pid] = ix;
}

// ---- K3: xp[b,p,:] = rmsnorm(emb[tok[b, idx[b,p]]], enc_norm_w). block per row ----
__global__ void k_xp(const int* __restrict__ tok, const int* __restrict__ idx,
                     const float* __restrict__ emb, const float* __restrict__ nw,
                     float* __restrict__ xp) {
    int pid = blockIdx.x;
    int b = pid / Pn;
    int tk = tok[b * Tn + idx[pid]];
    const float* row = emb + (long)tk * Dn;
    __shared__ float red[4];
    float v[4]; float ss = 0.f;
    #pragma unroll
    for (int j = 0; j < 4; j++) { v[j] = row[threadIdx.x + j * 256]; ss += v[j] * v[j]; }
    ss = blk_sum256(ss, red);
    float sc = 1.f / sqrtf(ss * (1.f / Dn) + 1e-6f);
    #pragma unroll
    for (int j = 0; j < 4; j++) {
        int d = threadIdx.x + j * 256;
        xp[(long)pid * Dn + d] = v[j] * sc * nw[d];
    }
}

// ---- K4: rl[b,p] = xp[b,p,:]·rw + ent. block per row ----
__global__ void k_router(const float* __restrict__ xp, const float* __restrict__ rw,
                         const float* __restrict__ ent, float* __restrict__ rl) {
    int pid = blockIdx.x;
    const float* xr = xp + (long)pid * Dn;
    __shared__ float red[4];
    float s = 0.f;
    #pragma unroll
    for (int j = 0; j < 4; j++) { int d = threadIdx.x + j * 256; s += xr[d] * rw[d]; }
    s = blk_sum256(s, red);
    if (threadIdx.x == 0) rl[pid] = s + ent[pid];
}

// ---- K5: exact top-k (KC of P) with jax tie semantics, output ascending by index ----
__global__ void k_topk(const float* __restrict__ rl, int* __restrict__ sel, float* __restrict__ g) {
    int b = blockIdx.x, p = threadIdx.x;
    __shared__ float vals[Pn];
    __shared__ int flag[Pn];
    float v = rl[b * Pn + p];
    vals[p] = v;
    __syncthreads();
    int rank = 0;
    for (int q = 0; q < Pn; q++) {
        float vq = vals[q];
        rank += (vq > v || (vq == v && q < p)) ? 1 : 0;
    }
    int selected = rank < KCn ? 1 : 0;
    flag[p] = selected;
    __syncthreads();
    if (selected) {
        int pos = 0;
        for (int q = 0; q < p; q++) pos += flag[q];
        sel[b * KCn + pos] = p;
        g[b * KCn + pos] = sigmf(v);
    }
}

// ---- K6: gather xs = xp[b, sel], h = rmsnorm(xs, ln1). block per (b,j) ----
__global__ void k_gather_ln1(const float* __restrict__ xp, const int* __restrict__ sel,
                             const float* __restrict__ w, float* __restrict__ xs,
                             float* __restrict__ h) {
    int r = blockIdx.x;            // b*KC + j
    int b = r / KCn;
    int p = sel[r];
    const float* src = xp + ((long)b * Pn + p) * Dn;
    __shared__ float red[4];
    float v[4]; float ss = 0.f;
    #pragma unroll
    for (int j = 0; j < 4; j++) { v[j] = src[threadIdx.x + j * 256]; ss += v[j] * v[j]; }
    ss = blk_sum256(ss, red);
    float sc = 1.f / sqrtf(ss * (1.f / Dn) + 1e-6f);
    #pragma unroll
    for (int j = 0; j < 4; j++) {
        int d = threadIdx.x + j * 256;
        xs[(long)r * Dn + d] = v[j];
        h[(long)r * Dn + d] = v[j] * sc * w[d];
    }
}

// ---- MFMA GEMM, fp32-accurate via bf16 hi/lo x3, double-buffered + split-K ----
// C[M,N] = A[M,K] @ W[K,N] (+bias). grid (ceil(N/128), M/128, splitK), block 256.
// splitK>1: epilogue atomicAdd (C must be pre-zeroed); bias added by chunk 0 only.
// M%128==0, (K/splitK)%32==0. N arbitrary.
constexpr int RS = 40;  // LDS row stride (bf16): frag ds_read_b128 lands 2-way bank alias (free, m136)
__global__ __launch_bounds__(256) void k_mfma(const float* __restrict__ A, const float* __restrict__ Wm,
                       float* __restrict__ Cmat, const float* __restrict__ bias,
                       int M, int N, int K, int splitK) {
    __shared__ alignas(16) unsigned short Ah[2][128 * RS], Al[2][128 * RS],
                                          Bh[2][128 * RS], Bl[2][128 * RS];
    int tid = threadIdx.x;
    int m0 = blockIdx.y * 128, n0 = blockIdx.x * 128;
    int kchunk = blockIdx.z;
    int Kc = K / splitK;
    int kbase = kchunk * Kc;
    int KT = Kc >> 5;
    int lane = tid & 63, wid = tid >> 6;
    int wm = (wid & 1) * 64, wn = (wid >> 1) * 64;
    int quad = lane >> 4, l16 = lane & 15;
    floatx4 acc[4][4];
    #pragma unroll
    for (int i = 0; i < 4; i++)
        #pragma unroll
        for (int j = 0; j < 4; j++) acc[i][j] = (floatx4){0.f, 0.f, 0.f, 0.f};

    int arow = tid >> 3, ak4 = (tid & 7) * 4;   // A: row = arow+32*r4, k-cols ak4..ak4+3
    int bkb = (tid >> 5) * 4, bn = tid & 31;    // B: k-rows bkb..bkb+3, n = bn+32*j (stride-1 coalesced)

    float4 av[4];
    float  bv[4][4];

    auto load_tile = [&](int k0) {
        #pragma unroll
        for (int r4 = 0; r4 < 4; r4++)
            av[r4] = *(const float4*)(A + (long)(m0 + arow + r4 * 32) * K + k0 + ak4);
        #pragma unroll
        for (int i = 0; i < 4; i++)
            #pragma unroll
            for (int j = 0; j < 4; j++) {
                int n = n0 + bn + 32 * j;
                bv[i][j] = (n < N) ? Wm[(long)(k0 + bkb + i) * N + n] : 0.f;
            }
    };
    auto stage_tile = [&](int buf) {
        #pragma unroll
        for (int r4 = 0; r4 < 4; r4++) {
            int row = arow + r4 * 32;
            unsigned short h0, h1, h2, h3, l0, l1, l2, l3;
            cvt_hilo(av[r4].x, h0, l0); cvt_hilo(av[r4].y, h1, l1);
            cvt_hilo(av[r4].z, h2, l2); cvt_hilo(av[r4].w, h3, l3);
            *(ushort4*)&Ah[buf][row * RS + ak4] = make_ushort4(h0, h1, h2, h3);
            *(ushort4*)&Al[buf][row * RS + ak4] = make_ushort4(l0, l1, l2, l3);
        }
        #pragma unroll
        for (int j = 0; j < 4; j++) {
            int n = bn + 32 * j;
            unsigned short h[4], l[4];
            #pragma unroll
            for (int i = 0; i < 4; i++) cvt_hilo(bv[i][j], h[i], l[i]);
            *(ushort4*)&Bh[buf][n * RS + bkb] = make_ushort4(h[0], h[1], h[2], h[3]);
            *(ushort4*)&Bl[buf][n * RS + bkb] = make_ushort4(l[0], l[1], l[2], l[3]);
        }
    };

    load_tile(kbase);
    stage_tile(0);
    __syncthreads();

    for (int ks = 0; ks < KT; ks++) {
        int cur = ks & 1;
        if (ks + 1 < KT) load_tile(kbase + (ks + 1) * 32);   // prefetch (vmcnt waits sink into stage)
        short8 ah[4], al2[4], bh[4], bl2[4];
        #pragma unroll
        for (int i = 0; i < 4; i++) {
            int r = wm + i * 16 + l16;
            ah[i]  = *(const short8*)&Ah[cur][r * RS + quad * 8];
            al2[i] = *(const short8*)&Al[cur][r * RS + quad * 8];
        }
        #pragma unroll
        for (int j = 0; j < 4; j++) {
            int c = wn + j * 16 + l16;
            bh[j]  = *(const short8*)&Bh[cur][c * RS + quad * 8];
            bl2[j] = *(const short8*)&Bl[cur][c * RS + quad * 8];
        }
        #pragma unroll
        for (int i = 0; i < 4; i++)
            #pragma unroll
            for (int j = 0; j < 4; j++) {
                acc[i][j] = __builtin_amdgcn_mfma_f32_16x16x32_bf16(ah[i],  bh[j],  acc[i][j], 0, 0, 0);
                acc[i][j] = __builtin_amdgcn_mfma_f32_16x16x32_bf16(ah[i],  bl2[j], acc[i][j], 0, 0, 0);
                acc[i][j] = __builtin_amdgcn_mfma_f32_16x16x32_bf16(al2[i], bh[j],  acc[i][j], 0, 0, 0);
            }
        if (ks + 1 < KT) stage_tile(cur ^ 1);
        __syncthreads();
    }

    // epilogue: C/D layout col=lane&15, row=quad*4+reg (m89/m91)
    #pragma unroll
    for (int j = 0; j < 4; j++) {
        int n = n0 + wn + j * 16 + l16;
        if (n >= N) continue;
        float bvx = (bias && kchunk == 0) ? bias[n] : 0.f;
        #pragma unroll
        for (int i = 0; i < 4; i++) {
            int mb = m0 + wm + i * 16 + quad * 4;
            #pragma unroll
            for (int r = 0; r < 4; r++) {
                float vv = acc[i][j][r] + bvx;
                if (splitK > 1) atomicAdd(&Cmat[(long)(mb + r) * N + n], vv);
                else            Cmat[(long)(mb + r) * N + n] = vv;
            }
        }
    }
}

// ---- RoPE in-place on (B*KC, nh*64), positions = sel[row] ----
__global__ void k_rope(float* __restrict__ buf, const int* __restrict__ sel, int nh) {
    int tid = blockIdx.x * blockDim.x + threadIdx.x;
    int total = Bn * KCn * nh * 32;
    if (tid >= total) return;
    int d = tid & 31;
    int h = (tid >> 5) % nh;
    int r = tid / (32 * nh);
    int pos = sel[r];
    float theta = powf(10000.f, -(float)(2 * d) / 64.f);
    float ang = (float)pos * theta;
    float c = cosf(ang), s = sinf(ang);
    long base = (long)r * (nh * 64) + h * 64 + d;
    float x1 = buf[base], x2 = buf[base + 32];
    buf[base]      = x1 * c - x2 * s;
    buf[base + 32] = x2 * c + x1 * s;
}

// ---- MFMA flash attention: block = (64 q-rows, h, b). 4 waves x 16 q-rows. ----
// S = QK^T via bf16 hi/lo x3 MFMA; softmax in regs (quad shuffles); P->LDS->A-frag;
// V^T staged in LDS; causal chunk skipping. APS=72 shorts: 2-way bank alias (free).
constexpr int APS = 72;
__global__ __launch_bounds__(256) void k_attn(const float* __restrict__ q, const float* __restrict__ k,
                       const float* __restrict__ v, float* __restrict__ aout) {
    int bx = blockIdx.x, h = blockIdx.y, b = blockIdx.z;
    int hk = h >> 2;
    int qb0 = bx * 64;
    int tid = threadIdx.x, lane = tid & 63, wid = tid >> 6;
    int quad = lane >> 4, l16 = lane & 15;
    __shared__ alignas(16) unsigned short LdsA[9216], LdsB[9216];
    unsigned short* Kh = LdsA;          unsigned short* Kl = LdsB;          // 128 x APS
    unsigned short* Ph = LdsA;          unsigned short* Pl = LdsB;          // 64 x APS (wave-sliced)
    unsigned short* Vth = LdsA + 4608;  unsigned short* Vtl = LdsB + 4608;  // 64 x APS

    // Q fragments (A-layout: m=l16 -> q-row, k=quad*8+j -> d), 2 ksteps of 32
    int qrow = qb0 + wid * 16 + l16;
    short8 qh[2], ql[2];
    #pragma unroll
    for (int ks = 0; ks < 2; ks++) {
        const float* qp = q + ((long)(b * KCn + qrow)) * (NHn * HDn) + h * HDn + ks * 32 + quad * 8;
        float tmp[8];
        *(float4*)tmp = *(const float4*)qp;
        *(float4*)(tmp + 4) = *(const float4*)(qp + 4);
        #pragma unroll
        for (int j = 0; j < 8; j++) {
            unsigned short hh, ll;
            cvt_hilo(tmp[j], hh, ll);
            qh[ks][j] = (short)hh; ql[ks][j] = (short)ll;
        }
    }

    floatx4 sacc[16];
    #pragma unroll
    for (int t = 0; t < 16; t++) sacc[t] = (floatx4){0.f, 0.f, 0.f, 0.f};

    int qmax = qb0 + 63;
    int nkc = qmax / 128 + 1;           // 1 or 2 chunks of 128 keys
    for (int kc = 0; kc < nkc; kc++) {
        __syncthreads();
        {   // stage K chunk: rows kc*128 + (tid>>1), d-half (tid&1)*32
            int r = tid >> 1, dh = (tid & 1) * 32;
            const float* kp = k + ((long)(b * KCn + kc * 128 + r)) * (NKVn * HDn) + hk * HDn + dh;
            #pragma unroll
            for (int f = 0; f < 8; f++) {
                float tmp[4];
                *(float4*)tmp = *(const float4*)(kp + f * 4);
                unsigned short h0, h1, h2, h3, l0, l1, l2, l3;
                cvt_hilo(tmp[0], h0, l0); cvt_hilo(tmp[1], h1, l1);
                cvt_hilo(tmp[2], h2, l2); cvt_hilo(tmp[3], h3, l3);
                *(ushort4*)&Kh[r * APS + dh + f * 4] = make_ushort4(h0, h1, h2, h3);
                *(ushort4*)&Kl[r * APS + dh + f * 4] = make_ushort4(l0, l1, l2, l3);
            }
        }
        __syncthreads();
        #pragma unroll
        for (int tj = 0; tj < 8; tj++) {
            int kr = tj * 16 + l16;     // local key row (B-frag: n=l16)
            int gt = kc * 8 + tj;
            #pragma unroll
            for (int ks = 0; ks < 2; ks++) {
                short8 bh0 = *(const short8*)&Kh[kr * APS + ks * 32 + quad * 8];
                short8 bl0 = *(const short8*)&Kl[kr * APS + ks * 32 + quad * 8];
                sacc[gt] = __builtin_amdgcn_mfma_f32_16x16x32_bf16(qh[ks], bh0, sacc[gt], 0, 0, 0);
                sacc[gt] = __builtin_amdgcn_mfma_f32_16x16x32_bf16(qh[ks], bl0, sacc[gt], 0, 0, 0);
                sacc[gt] = __builtin_amdgcn_mfma_f32_16x16x32_bf16(ql[ks], bh0, sacc[gt], 0, 0, 0);
            }
        }
    }

    // scale + causal mask (C layout: row=quad*4+r, col(key)=t*16+l16), softmax per row
    float rowinv[4];
    #pragma unroll
    for (int r = 0; r < 4; r++) {
        int qg = qb0 + wid * 16 + quad * 4 + r;
        float mm = -3.4e38f;
        #pragma unroll
        for (int t = 0; t < 16; t++) {
            int key = t * 16 + l16;
            float s = (key <= qg) ? sacc[t][r] * 0.125f : -1e30f;
            sacc[t][r] = s;
            mm = fmaxf(mm, s);
        }
        #pragma unroll
        for (int o = 1; o < 16; o <<= 1) mm = fmaxf(mm, __shfl_xor(mm, o));
        float zz = 0.f;
        #pragma unroll
        for (int t = 0; t < 16; t++) {
            float e = expf(sacc[t][r] - mm);
            sacc[t][r] = e; zz += e;
        }
        #pragma unroll
        for (int o = 1; o < 16; o <<= 1) zz += __shfl_xor(zz, o);
        rowinv[r] = 1.f / zz;
    }

    // PV: O[16 q-rows][64 d] accumulated over 64-key chunks
    floatx4 oacc[4];
    #pragma unroll
    for (int dt = 0; dt < 4; dt++) oacc[dt] = (floatx4){0.f, 0.f, 0.f, 0.f};
    int npv = qmax / 64 + 1;            // bx+1 chunks
    for (int c4 = 0; c4 < npv; c4++) {
        __syncthreads();
        {   // stage V^T chunk: Vt[d][kloc], keys c4*64..+63
            #pragma unroll
            for (int it = 0; it < 4; it++) {
                int task = tid + 256 * it;
                int kloc = task & 63, d4 = (task >> 6) * 4;
                float tmp[4];
                *(float4*)tmp = *(const float4*)(v + ((long)(b * KCn + c4 * 64 + kloc)) * (NKVn * HDn) + hk * HDn + d4);
                #pragma unroll
                for (int i = 0; i < 4; i++) {
                    unsigned short hh, ll;
                    cvt_hilo(tmp[i], hh, ll);
                    Vth[(d4 + i) * APS + kloc] = hh;
                    Vtl[(d4 + i) * APS + kloc] = ll;
                }
            }
        }
        // write P chunk (tiles 4*c4..+3) into wave's 16-row region
        #pragma unroll
        for (int tt = 0; tt < 4; tt++) {
            int t = c4 * 4 + tt;
            #pragma unroll
            for (int r = 0; r < 4; r++) {
                int row = wid * 16 + quad * 4 + r;
                float pv2 = sacc[t][r] * rowinv[r];
                unsigned short hh, ll;
                cvt_hilo(pv2, hh, ll);
                Ph[row * APS + tt * 16 + l16] = hh;
                Pl[row * APS + tt * 16 + l16] = ll;
            }
        }
        __syncthreads();
        short8 pah[2], pal[2];
        #pragma unroll
        for (int ks = 0; ks < 2; ks++) {
            pah[ks] = *(const short8*)&Ph[(wid * 16 + l16) * APS + ks * 32 + quad * 8];
            pal[ks] = *(const short8*)&Pl[(wid * 16 + l16) * APS + ks * 32 + quad * 8];
        }
        #pragma unroll
        for (int dt = 0; dt < 4; dt++) {
            #pragma unroll
            for (int ks = 0; ks < 2; ks++) {
                short8 vbh = *(const short8*)&Vth[(dt * 16 + l16) * APS + ks * 32 + quad * 8];
                short8 vbl = *(const short8*)&Vtl[(dt * 16 + l16) * APS + ks * 32 + quad * 8];
                oacc[dt] = __builtin_amdgcn_mfma_f32_16x16x32_bf16(pah[ks], vbh, oacc[dt], 0, 0, 0);
                oacc[dt] = __builtin_amdgcn_mfma_f32_16x16x32_bf16(pah[ks], vbl, oacc[dt], 0, 0, 0);
                oacc[dt] = __builtin_amdgcn_mfma_f32_16x16x32_bf16(pal[ks], vbh, oacc[dt], 0, 0, 0);
            }
        }
    }

    // epilogue: O C-layout row=quad*4+r, col(d within tile)=l16
    #pragma unroll
    for (int dt = 0; dt < 4; dt++) {
        #pragma unroll
        for (int r = 0; r < 4; r++) {
            int row = qb0 + wid * 16 + quad * 4 + r;
            aout[((long)(b * KCn + row)) * (NHn * HDn) + h * HDn + dt * 16 + l16] = oacc[dt][r];
        }
    }
}

// ---- x2 = xs + ao; h2 = rmsnorm(x2, ln2). block per row ----
__global__ void k_add_ln2(const float* __restrict__ xs, const float* __restrict__ ao,
                          const float* __restrict__ w, float* __restrict__ h2) {
    int r = blockIdx.x;
    __shared__ float red[4];
    float v[4]; float ss = 0.f;
    #pragma unroll
    for (int j = 0; j < 4; j++) {
        int d = threadIdx.x + j * 256;
        float x = xs[(long)r * Dn + d] + ao[(long)r * Dn + d];
        v[j] = x; ss += x * x;
    }
    ss = blk_sum256(ss, red);
    float sc = 1.f / sqrtf(ss * (1.f / Dn) + 1e-6f);
    #pragma unroll
    for (int j = 0; j < 4; j++) {
        int d = threadIdx.x + j * 256;
        h2[(long)r * Dn + d] = v[j] * sc * w[d];
    }
}

// ---- gact = silu(gact)*uact ----
__global__ void k_silu_mul(float* __restrict__ gact, const float* __restrict__ uact, int n) {
    int i = blockIdx.x * blockDim.x + threadIdx.x;
    if (i < n) { float x = gact[i]; gact[i] = x * sigmf(x) * uact[i]; }
}

// ---- xp[b, sel[b,j], :] += g * (ao + ff). block per (b,j) ----
__global__ void k_scatter(float* __restrict__ xp, const float* __restrict__ ao,
                          const float* __restrict__ ff, const float* __restrict__ g,
                          const int* __restrict__ sel) {
    int r = blockIdx.x;
    int b = r / KCn;
    int p = sel[r];
    float gg = g[r];
    float* dst = xp + ((long)b * Pn + p) * Dn;
    #pragma unroll
    for (int j = 0; j < 4; j++) {
        int d = threadIdx.x + j * 256;
        dst[d] += gg * (ao[(long)r * Dn + d] + ff[(long)r * Dn + d]);
    }
}

// ---- win = sigmoid(gelu(hmlp) @ w2 + b2). gelu applied here (splitK GEMM can't fuse act) ----
__global__ void k_win(const float* __restrict__ hmlp, const float* __restrict__ w2,
                      const float* __restrict__ b2, float* __restrict__ win) {
    int tid = blockIdx.x * blockDim.x + threadIdx.x;
    if (tid >= Bn * Pn * Sn) return;
    int s = tid & 3; int r = tid >> 2;
    float acc = b2[s];
    const float* hr = hmlp + (long)r * 256;
    for (int i = 0; i < 256; i++) acc += geluf(hr[i]) * w2[i * 4 + s];
    win[tid] = sigmf(acc);
}

// ---- y = rmsnorm(proj*win, dec_norm_w). block per row (8192 rows) ----
__global__ void k_dec_norm(const float* __restrict__ proj, const float* __restrict__ win,
                           const float* __restrict__ w, float* __restrict__ y) {
    int r = blockIdx.x;
    float wv = win[r];
    __shared__ float red[4];
    float v[4]; float ss = 0.f;
    #pragma unroll
    for (int j = 0; j < 4; j++) {
        int d = threadIdx.x + j * 256;
        float x = proj[(long)r * Dn + d] * wv;
        v[j] = x; ss += x * x;
    }
    ss = blk_sum256(ss, red);
    float sc = 1.f / sqrtf(ss * (1.f / Dn) + 1e-6f);
    #pragma unroll
    for (int j = 0; j < 4; j++) {
        int d = threadIdx.x + j * 256;
        y[(long)r * Dn + d] = v[j] * sc * w[d];
    }
}

extern "C" void kernel_launch(void* const* d_in, const int* in_sizes, int n_in,
                              void* d_out, int out_size, void* d_ws, size_t ws_size,
                              hipStream_t stream) {
    const int*   tokens     = (const int*)  d_in[0];
    const float* emb        = (const float*)d_in[1];
    const float* bp_w1      = (const float*)d_in[2];
    const float* bp_b1      = (const float*)d_in[3];
    const float* bp_w2      = (const float*)d_in[4];
    const float* bp_b2      = (const float*)d_in[5];
    const float* enc_norm_w = (const float*)d_in[6];
    const float* router_w   = (const float*)d_in[7];
    const float* ln1_w      = (const float*)d_in[8];
    const float* ln2_w      = (const float*)d_in[9];
    const float* q_w        = (const float*)d_in[10];
    const float* k_w        = (const float*)d_in[11];
    const float* v_w        = (const float*)d_in[12];
    const float* o_w        = (const float*)d_in[13];
    const float* gate_w     = (const float*)d_in[14];
    const float* up_w       = (const float*)d_in[15];
    const float* down_w     = (const float*)d_in[16];
    const float* dec_proj_w = (const float*)d_in[17];
    const float* dec_proj_b = (const float*)d_in[18];
    const float* dec_mlp_w1 = (const float*)d_in[19];
    const float* dec_mlp_b1 = (const float*)d_in[20];
    const float* dec_mlp_w2 = (const float*)d_in[21];
    const float* dec_mlp_b2 = (const float*)d_in[22];
    const float* dec_norm_w = (const float*)d_in[23];
    const float* head_w     = (const float*)d_in[24];
    float* out = (float*)d_out;

    float* W = (float*)d_ws;
    float* EW   = W + OFF_EW;
    float* cA   = W + OFF_CA;
    float* cB   = W + OFF_CB;
    float* cC   = W + OFF_CC;
    float* ent  = W + OFF_ENT;
    int*   idxb = (int*)(W + OFF_IDX);
    float* xp   = W + OFF_XP;
    float* rl   = W + OFF_RL;
    int*   sel  = (int*)(W + OFF_SEL);
    float* g    = W + OFF_G;
    float* scr  = W + SCR;
    float* xs   = scr + SC_XS;
    float* h    = scr + SC_H;
    float* qb   = scr + SC_Q;
    float* kb   = scr + SC_K;
    float* vb   = scr + SC_V;
    float* aout = scr + SC_AOUT;
    float* ao   = scr + SC_AO;
    float* h2   = scr + SC_H2;
    float* gact = scr + SC_GACT;
    float* uact = scr + SC_UACT;
    float* ffb  = scr + SC_FF;
    float* proj = scr + SC_PROJ;
    float* hmlp = scr + SC_HMLP;
    float* win  = scr + SC_WIN;
    float* y    = scr + SC_Y;

    // byte-patch encoder
    k_ew<<<dim3(96, 17), dim3(16, 16), 0, stream>>>(emb, bp_w1, EW);
    k_conv1<<<Bn * Tn / 4, 256, 0, stream>>>(tokens, EW, bp_b1, bp_w2, cA, cB, cC);
    k_patchstats<<<(Bn * Pn + 255) / 256, 256, 0, stream>>>(cA, cB, cC, bp_b2, ent, idxb);
    k_xp<<<Bn * Pn, 256, 0, stream>>>(tokens, idxb, emb, enc_norm_w, xp);

    for (int l = 0; l < Ln; l++) {
        k_router<<<Bn * Pn, 256, 0, stream>>>(xp, router_w + (long)l * Dn, ent, rl);
        k_topk<<<Bn, Pn, 0, stream>>>(rl, sel, g);
        k_gather_ln1<<<Bn * KCn, 256, 0, stream>>>(xp, sel, ln1_w + (long)l * Dn, xs, h);
        // zero atomic-accumulated GEMM outputs (qb..vb contiguous 1.5M floats)
        k_zero<<<(1572864 / 4 + 255) / 256, 256, 0, stream>>>(qb, 1572864);
        k_zero<<<(1048576 / 4 + 255) / 256, 256, 0, stream>>>(ao, 1048576);
        k_zero<<<(1048576 / 4 + 255) / 256, 256, 0, stream>>>(ffb, 1048576);
        k_mfma<<<dim3(8, 8, 4),  256, 0, stream>>>(h, q_w + (long)l * Dn * Dn, qb, nullptr, 1024, 1024, 1024, 4);
        k_mfma<<<dim3(2, 8, 8),  256, 0, stream>>>(h, k_w + (long)l * Dn * 256, kb, nullptr, 1024, 256, 1024, 8);
        k_mfma<<<dim3(2, 8, 8),  256, 0, stream>>>(h, v_w + (long)l * Dn * 256, vb, nullptr, 1024, 256, 1024, 8);
        k_rope<<<(Bn * KCn * NHn * 32 + 255) / 256, 256, 0, stream>>>(qb, sel, NHn);
        k_rope<<<(Bn * KCn * NKVn * 32 + 255) / 256, 256, 0, stream>>>(kb, sel, NKVn);
        k_attn<<<dim3(4, NHn, Bn), 256, 0, stream>>>(qb, kb, vb, aout);
        k_mfma<<<dim3(8, 8, 4),  256, 0, stream>>>(aout, o_w + (long)l * Dn * Dn, ao, nullptr, 1024, 1024, 1024, 4);
        k_add_ln2<<<Bn * KCn, 256, 0, stream>>>(xs, ao, ln2_w + (long)l * Dn, h2);
        k_mfma<<<dim3(32, 8, 1), 256, 0, stream>>>(h2, gate_w + (long)l * Dn * FFn, gact, nullptr, 1024, 4096, 1024, 1);
        k_mfma<<<dim3(32, 8, 1), 256, 0, stream>>>(h2, up_w + (long)l * Dn * FFn, uact, nullptr, 1024, 4096, 1024, 1);
        k_silu_mul<<<(Bn * KCn * FFn + 255) / 256, 256, 0, stream>>>(gact, uact, Bn * KCn * FFn);
        k_mfma<<<dim3(8, 8, 4),  256, 0, stream>>>(gact, down_w + (long)l * FFn * Dn, ffb, nullptr, 1024, 1024, 4096, 4);
        k_scatter<<<Bn * KCn, 256, 0, stream>>>(xp, ao, ffb, g, sel);
    }

    // decoder
    k_mfma<<<dim3(32, 16, 1), 256, 0, stream>>>(xp, dec_proj_w, proj, dec_proj_b, 2048, 4096, 1024, 1);
    k_zero<<<(524288 / 4 + 255) / 256, 256, 0, stream>>>(hmlp, 524288);
    k_mfma<<<dim3(2, 16, 4),  256, 0, stream>>>(xp, dec_mlp_w1, hmlp, dec_mlp_b1, 2048, 256, 1024, 4);
    k_win<<<(Bn * Pn * Sn + 255) / 256, 256, 0, stream>>>(hmlp, dec_mlp_w2, dec_mlp_b2, win);
    k_dec_norm<<<Bn * Pn * Sn, 256, 0, stream>>>(proj, win, dec_norm_w, y);
    k_mfma<<<dim3(3, 64, 1),  256, 0, stream>>>(y, head_w, out, nullptr, 8192, 257, 1024, 1);
}

// Round 5
// 1796.051 us; speedup vs baseline: 3.1627x; 1.1715x over previous
//
#include <hip/hip_runtime.h>
#include <hip/hip_bf16.h>
#include <math.h>

// ---- model dims ----
constexpr int Bn  = 4;
constexpr int Tn  = 8192;
constexpr int Dn  = 1024;
constexpr int Pn  = 512;
constexpr int SEGn= 16;     // T/P
constexpr int Sn  = 4;
constexpr int Ln  = 4;
constexpr int NHn = 16;
constexpr int NKVn= 4;
constexpr int HDn = 64;
constexpr int FFn = 4096;
constexpr int KCn = 256;
constexpr int Vn  = 257;
constexpr int DHn = 512;    // conv hidden (D/2)

// ---- workspace layout (float elements). total = 33,015,296 floats = 126 MB ----
constexpr long OFF_EW  = 0;                       // 3*257*512 = 394752
constexpr long OFF_CA  = 394752;                  // B*T
constexpr long OFF_CB  = 427520;
constexpr long OFF_CC  = 460288;
constexpr long OFF_ENT = 493056;                  // B*P
constexpr long OFF_IDX = 495104;                  // B*P (int)
constexpr long OFF_XP  = 497152;                  // B*P*D = 2097152
constexpr long OFF_RL  = 2594304;                 // B*P
constexpr long OFF_SEL = 2596352;                 // B*KC (int)
constexpr long OFF_G   = 2597376;                 // B*KC
constexpr long SCR     = 2598400;
// layer-phase scratch (offsets relative to SCR):
constexpr long SC_XS   = 0;         // 1048576
constexpr long SC_H    = 1048576;   // 1048576 (as hi/lo ushort pair)
constexpr long SC_Q    = 2097152;   // 1048576
constexpr long SC_K    = 3145728;   // 262144
constexpr long SC_V    = 3407872;   // 262144
constexpr long SC_AOUT = 3670016;   // 1048576 (hi/lo)
constexpr long SC_AO   = 4718592;   // 1048576
constexpr long SC_H2   = 5767168;   // 1048576 (hi/lo)
constexpr long SC_GACT = 6815744;   // 4194304
constexpr long SC_UACT = 11010048;  // 4194304
constexpr long SC_FF   = 15204352;  // 1048576
// decoder-phase (overlays layer region):
constexpr long SC_PROJ = 0;         // 8388608
constexpr long SC_HMLP = 8388608;   // 524288
constexpr long SC_WIN  = 8912896;   // 8192
constexpr long SC_Y    = 8921088;   // 8388608 (hi/lo)
// new regions (absolute float offsets in ws):
constexpr long OFF_WT    = 19908096;  // 4M floats: WTh 4M ushort + WTl 4M ushort
constexpr long OFF_PARTS = 24102400;  // 4718592 floats (max: head 2*8192*257)
constexpr long OFF_GHL   = 28820992;  // 4M floats: gact/xp hi+lo
// total 33015296

typedef __attribute__((ext_vector_type(8))) short short8;
typedef __attribute__((ext_vector_type(4))) float floatx4;

// ---- helpers ----
__device__ __forceinline__ float geluf(float x) {
    float x3 = x * x * x;
    return 0.5f * x * (1.f + tanhf(0.7978845608028654f * (x + 0.044715f * x3)));
}
__device__ __forceinline__ float sigmf(float x) { return 1.f / (1.f + expf(-x)); }

// fp32 -> bf16 hi/lo split (truncation; x ~= hi + lo, err ~2^-17 rel)
__device__ __forceinline__ void cvt_hilo(float x, unsigned short& h, unsigned short& l) {
    unsigned u = __float_as_uint(x);
    h = (unsigned short)(u >> 16);
    float r = x - __uint_as_float(u & 0xffff0000u);
    l = (unsigned short)(__float_as_uint(r) >> 16);
}

// block (256 threads) sum reduce; red must be __shared__ float[4]
__device__ __forceinline__ float blk_sum256(float v, float* red) {
    for (int o = 32; o > 0; o >>= 1) v += __shfl_down(v, o);
    int lane = threadIdx.x & 63, w = threadIdx.x >> 6;
    if (lane == 0) red[w] = v;
    __syncthreads();
    float r = red[0] + red[1] + red[2] + red[3];
    __syncthreads();
    return r;
}

// ---- K0: EW[dk][v][o] = sum_i emb[v,i] * w1[o,i,dk] ----
__global__ void k_ew(const float* __restrict__ emb, const float* __restrict__ w1,
                     float* __restrict__ EW) {
    __shared__ float As[16][17];
    __shared__ float Ws[16][17];
    int c0 = blockIdx.x * 16, v0 = blockIdx.y * 16;
    int tx = threadIdx.x, ty = threadIdx.y;
    float acc = 0.f;
    int c = c0 + tx;
    int o = c / 3, dk = c - o * 3;
    for (int k0 = 0; k0 < Dn; k0 += 16) {
        int v = v0 + ty;
        As[ty][tx] = (v < Vn) ? emb[v * Dn + k0 + tx] : 0.f;
        Ws[ty][tx] = w1[o * 3072 + (k0 + ty) * 3 + dk];
        __syncthreads();
        #pragma unroll
        for (int kk = 0; kk < 16; kk++) acc += As[ty][kk] * Ws[kk][tx];
        __syncthreads();
    }
    int v = v0 + ty;
    if (v < Vn) EW[(long)dk * (Vn * DHn) + (long)v * DHn + o] = acc;
}

// ---- K1: per (b,t): h1 column via EW lookups + gelu, reduce to 3 dots with w2 ----
__global__ void k_conv1(const int* __restrict__ tok, const float* __restrict__ EW,
                        const float* __restrict__ b1, const float* __restrict__ w2,
                        float* __restrict__ cA, float* __restrict__ cB, float* __restrict__ cC) {
    int wave = threadIdx.x >> 6, lane = threadIdx.x & 63;
    int gidx = blockIdx.x * 4 + wave;     // b*T + t
    int b = gidx / Tn, t = gidx - b * Tn;
    int tk  = tok[b * Tn + t];
    int tkm = (t > 0)      ? tok[b * Tn + t - 1] : -1;
    int tkp = (t < Tn - 1) ? tok[b * Tn + t + 1] : -1;
    const float* E0 = EW;
    const float* E1 = EW + (long)Vn * DHn;
    const float* E2 = EW + 2L * Vn * DHn;
    float a0 = 0.f, a1 = 0.f, a2 = 0.f;
    #pragma unroll
    for (int u = 0; u < DHn / 64; u++) {
        int o = lane + u * 64;
        float s = b1[o] + E1[tk * DHn + o];
        if (tkm >= 0) s += E0[tkm * DHn + o];
        if (tkp >= 0) s += E2[tkp * DHn + o];
        float hg = geluf(s);
        a0 += hg * w2[o * 3 + 0];
        a1 += hg * w2[o * 3 + 1];
        a2 += hg * w2[o * 3 + 2];
    }
    for (int o = 32; o > 0; o >>= 1) {
        a0 += __shfl_down(a0, o); a1 += __shfl_down(a1, o); a2 += __shfl_down(a2, o);
    }
    if (lane == 0) { cA[gidx] = a0; cB[gidx] = a1; cC[gidx] = a2; }
}

// ---- K2: lg per token -> per-patch softmax -> ent, idx ----
__global__ void k_patchstats(const float* __restrict__ cA, const float* __restrict__ cB,
                             const float* __restrict__ cC, const float* __restrict__ b2,
                             float* __restrict__ ent_out, int* __restrict__ idx_out) {
    int pid = blockIdx.x * blockDim.x + threadIdx.x;   // b*P + p
    if (pid >= Bn * Pn) return;
    int b = pid / Pn, p = pid - b * Pn;
    float lgv[SEGn];
    float m = -3.4e38f;
    for (int s = 0; s < SEGn; s++) {
        int t = p * SEGn + s;
        float v = b2[0] + cB[b * Tn + t];
        if (t > 0)      v += cA[b * Tn + t - 1];
        if (t < Tn - 1) v += cC[b * Tn + t + 1];
        lgv[s] = v; m = fmaxf(m, v);
    }
    float Z = 0.f;
    for (int s = 0; s < SEGn; s++) { lgv[s] = expf(lgv[s] - m); Z += lgv[s]; }
    float inv = 1.f / Z;
    float bp = 0.f, en = 0.f;
    for (int s = 0; s < SEGn; s++) {
        float w = lgv[s] * inv;
        bp += w * (float)(p * SEGn + s);
        en -= w * logf(fmaxf(w, 1e-8f));
    }
    en *= (1.f / 2.772588722239781f);   // / ln(16)
    ent_out[pid] = en;
    int ix = (int)bp;
    ix = ix < 0 ? 0 : (ix > Tn - 1 ? Tn - 1 : ix);
    idx_out[pid] = ix;
}

// ---- K3: xp[b,p,:] = rmsnorm(emb[tok[b, idx[b,p]]], enc_norm_w). block per row ----
__global__ void k_xp(const int* __restrict__ tok, const int* __restrict__ idx,
                     const float* __restrict__ emb, const float* __restrict__ nw,
                     float* __restrict__ xp) {
    int pid = blockIdx.x;
    int b = pid / Pn;
    int tk = tok[b * Tn + idx[pid]];
    const float* row = emb + (long)tk * Dn;
    __shared__ float red[4];
    float v[4]; float ss = 0.f;
    #pragma unroll
    for (int j = 0; j < 4; j++) { v[j] = row[threadIdx.x + j * 256]; ss += v[j] * v[j]; }
    ss = blk_sum256(ss, red);
    float sc = 1.f / sqrtf(ss * (1.f / Dn) + 1e-6f);
    #pragma unroll
    for (int j = 0; j < 4; j++) {
        int d = threadIdx.x + j * 256;
        xp[(long)pid * Dn + d] = v[j] * sc * nw[d];
    }
}

// ---- K4: rl[b,p] = xp[b,p,:]·rw + ent. block per row ----
__global__ void k_router(const float* __restrict__ xp, const float* __restrict__ rw,
                         const float* __restrict__ ent, float* __restrict__ rl) {
    int pid = blockIdx.x;
    const float* xr = xp + (long)pid * Dn;
    __shared__ float red[4];
    float s = 0.f;
    #pragma unroll
    for (int j = 0; j < 4; j++) { int d = threadIdx.x + j * 256; s += xr[d] * rw[d]; }
    s = blk_sum256(s, red);
    if (threadIdx.x == 0) rl[pid] = s + ent[pid];
}

// ---- K5: exact top-k (KC of P) with jax tie semantics, output ascending by index ----
__global__ void k_topk(const float* __restrict__ rl, int* __restrict__ sel, float* __restrict__ g) {
    int b = blockIdx.x, p = threadIdx.x;
    __shared__ float vals[Pn];
    __shared__ int flag[Pn];
    float v = rl[b * Pn + p];
    vals[p] = v;
    __syncthreads();
    int rank = 0;
    for (int q = 0; q < Pn; q++) {
        float vq = vals[q];
        rank += (vq > v || (vq == v && q < p)) ? 1 : 0;
    }
    int selected = rank < KCn ? 1 : 0;
    flag[p] = selected;
    __syncthreads();
    if (selected) {
        int pos = 0;
        for (int q = 0; q < p; q++) pos += flag[q];
        sel[b * KCn + pos] = p;
        g[b * KCn + pos] = sigmf(v);
    }
}

// ---- K6: gather xs = xp[b, sel]; h = rmsnorm(xs, ln1) emitted as hi/lo ----
__global__ void k_gather_ln1(const float* __restrict__ xp, const int* __restrict__ sel,
                             const float* __restrict__ w, float* __restrict__ xs,
                             unsigned short* __restrict__ hH, unsigned short* __restrict__ hL) {
    int r = blockIdx.x;            // b*KC + j
    int b = r / KCn;
    int p = sel[r];
    const float* src = xp + ((long)b * Pn + p) * Dn;
    __shared__ float red[4];
    float v[4]; float ss = 0.f;
    #pragma unroll
    for (int j = 0; j < 4; j++) { v[j] = src[threadIdx.x + j * 256]; ss += v[j] * v[j]; }
    ss = blk_sum256(ss, red);
    float sc = 1.f / sqrtf(ss * (1.f / Dn) + 1e-6f);
    #pragma unroll
    for (int j = 0; j < 4; j++) {
        int d = threadIdx.x + j * 256;
        xs[(long)r * Dn + d] = v[j];
        unsigned short hh, ll;
        cvt_hilo(v[j] * sc * w[d], hh, ll);
        hH[(long)r * Dn + d] = hh;
        hL[(long)r * Dn + d] = ll;
    }
}

// ---- weight convert+transpose: W[K][N] fp32 -> WT_hi[N][K], WT_lo[N][K] ushort ----
// grid (ceil(N/32), K/32), block 256 (=32x8)
__global__ void k_wconv(const float* __restrict__ Wm, unsigned short* __restrict__ Th,
                        unsigned short* __restrict__ Tl, int K, int N) {
    __shared__ float t[32][33];
    int n0 = blockIdx.x * 32, k0 = blockIdx.y * 32;
    int tx = threadIdx.x & 31, ty = threadIdx.x >> 5;
    #pragma unroll
    for (int r = 0; r < 4; r++) {
        int k = k0 + ty + 8 * r, n = n0 + tx;
        t[ty + 8 * r][tx] = (n < N) ? Wm[(long)k * N + n] : 0.f;
    }
    __syncthreads();
    #pragma unroll
    for (int r = 0; r < 4; r++) {
        int n = n0 + ty + 8 * r, k = k0 + tx;
        float v = t[tx][ty + 8 * r];
        unsigned short hh, ll;
        cvt_hilo(v, hh, ll);
        Th[(long)n * K + k] = hh;
        Tl[(long)n * K + k] = ll;
    }
}

// ---- elementwise fp32 -> hi/lo ----
__global__ void k_aconv(const float* __restrict__ src, unsigned short* __restrict__ dh,
                        unsigned short* __restrict__ dl, int n) {
    int i = blockIdx.x * blockDim.x + threadIdx.x;
    if (i >= n) return;
    unsigned short hh, ll;
    cvt_hilo(src[i], hh, ll);
    dh[i] = hh; dl[i] = ll;
}

// ---- MFMA GEMM on pre-split hi/lo operands. A[M][K], B=WT[N][K] (both ushort hi/lo).
// grid (ceil(N/128), M/128, splitK), block 256. splitK>1 -> parts[kc][M*N]; else C(+bias).
// M%128==0, (K/splitK)%32==0.
constexpr int RS2 = 40;  // LDS row stride: frag/stage land 2-way bank alias (free, m136)
__global__ __launch_bounds__(256, 2) void k_mfma2(
        const unsigned short* __restrict__ Agh, const unsigned short* __restrict__ Agl,
        const unsigned short* __restrict__ Bgh, const unsigned short* __restrict__ Bgl,
        float* __restrict__ Cmat, const float* __restrict__ bias,
        int M, int N, int K, int splitK, float* __restrict__ parts) {
    __shared__ alignas(16) unsigned short Ah[128 * RS2], Al[128 * RS2],
                                          Bh[128 * RS2], Bl[128 * RS2];
    int tid = threadIdx.x;
    int m0 = blockIdx.y * 128, n0 = blockIdx.x * 128;
    int kc = blockIdx.z;
    int Kc = K / splitK, kbase = kc * Kc, KT = Kc >> 5;
    int lane = tid & 63, wid = tid >> 6;
    int wm = (wid & 1) * 64, wn = (wid >> 1) * 64;
    int quad = lane >> 4, l16 = lane & 15;
    int srow = tid >> 1, koff = (tid & 1) * 16;
    long abase = (long)(m0 + srow) * K + koff;
    long bbase = (long)(n0 + srow) * K + koff;   // OOB rows (head pad) read garbage, never stored
    floatx4 acc[4][4];
    #pragma unroll
    for (int i = 0; i < 4; i++)
        #pragma unroll
        for (int j = 0; j < 4; j++) acc[i][j] = (floatx4){0.f, 0.f, 0.f, 0.f};

    short8 rah0, rah1, ral0, ral1, rbh0, rbh1, rbl0, rbl1;
    auto load = [&](int k0) {
        rah0 = *(const short8*)&Agh[abase + k0]; rah1 = *(const short8*)&Agh[abase + k0 + 8];
        ral0 = *(const short8*)&Agl[abase + k0]; ral1 = *(const short8*)&Agl[abase + k0 + 8];
        rbh0 = *(const short8*)&Bgh[bbase + k0]; rbh1 = *(const short8*)&Bgh[bbase + k0 + 8];
        rbl0 = *(const short8*)&Bgl[bbase + k0]; rbl1 = *(const short8*)&Bgl[bbase + k0 + 8];
    };
    auto stage = [&]() {
        *(short8*)&Ah[srow * RS2 + koff] = rah0; *(short8*)&Ah[srow * RS2 + koff + 8] = rah1;
        *(short8*)&Al[srow * RS2 + koff] = ral0; *(short8*)&Al[srow * RS2 + koff + 8] = ral1;
        *(short8*)&Bh[srow * RS2 + koff] = rbh0; *(short8*)&Bh[srow * RS2 + koff + 8] = rbh1;
        *(short8*)&Bl[srow * RS2 + koff] = rbl0; *(short8*)&Bl[srow * RS2 + koff + 8] = rbl1;
    };

    load(kbase);
    for (int ks = 0; ks < KT; ks++) {
        if (ks > 0) __syncthreads();        // WAR: all reads of prev tile done
        stage();
        __syncthreads();
        if (ks + 1 < KT) load(kbase + (ks + 1) * 32);
        short8 ah[4], al2[4], bh[4], bl2[4];
        #pragma unroll
        for (int i = 0; i < 4; i++) {
            int r = wm + i * 16 + l16;
            ah[i]  = *(const short8*)&Ah[r * RS2 + quad * 8];
            al2[i] = *(const short8*)&Al[r * RS2 + quad * 8];
        }
        #pragma unroll
        for (int j = 0; j < 4; j++) {
            int c = wn + j * 16 + l16;
            bh[j]  = *(const short8*)&Bh[c * RS2 + quad * 8];
            bl2[j] = *(const short8*)&Bl[c * RS2 + quad * 8];
        }
        #pragma unroll
        for (int i = 0; i < 4; i++)
            #pragma unroll
            for (int j = 0; j < 4; j++) {
                acc[i][j] = __builtin_amdgcn_mfma_f32_16x16x32_bf16(ah[i],  bh[j],  acc[i][j], 0, 0, 0);
                acc[i][j] = __builtin_amdgcn_mfma_f32_16x16x32_bf16(ah[i],  bl2[j], acc[i][j], 0, 0, 0);
                acc[i][j] = __builtin_amdgcn_mfma_f32_16x16x32_bf16(al2[i], bh[j],  acc[i][j], 0, 0, 0);
            }
    }

    // epilogue: C/D layout col=lane&15, row=quad*4+reg (m89/m91)
    long MN = (long)M * N;
    #pragma unroll
    for (int j = 0; j < 4; j++) {
        int n = n0 + wn + j * 16 + l16;
        if (n >= N) continue;
        float bvx = bias ? bias[n] : 0.f;
        #pragma unroll
        for (int i = 0; i < 4; i++) {
            int mb = m0 + wm + i * 16 + quad * 4;
            #pragma unroll
            for (int r = 0; r < 4; r++) {
                if (splitK > 1) parts[kc * MN + (long)(mb + r) * N + n] = acc[i][j][r];
                else            Cmat[(long)(mb + r) * N + n] = acc[i][j][r] + bvx;
            }
        }
    }
}

// ---- reduce splitK partials (+optional bias) ----
__global__ void k_reduce(const float* __restrict__ parts, float* __restrict__ out,
                         const float* __restrict__ bias, long MN, int sk, int N) {
    long i = (long)blockIdx.x * blockDim.x + threadIdx.x;
    if (i >= MN) return;
    float s = 0.f;
    for (int c = 0; c < sk; c++) s += parts[c * MN + i];
    if (bias) s += bias[(int)(i % N)];
    out[i] = s;
}

// ---- RoPE in-place on (B*KC, nh*64), positions = sel[row] ----
__global__ void k_rope(float* __restrict__ buf, const int* __restrict__ sel, int nh) {
    int tid = blockIdx.x * blockDim.x + threadIdx.x;
    int total = Bn * KCn * nh * 32;
    if (tid >= total) return;
    int d = tid & 31;
    int h = (tid >> 5) % nh;
    int r = tid / (32 * nh);
    int pos = sel[r];
    float theta = powf(10000.f, -(float)(2 * d) / 64.f);
    float ang = (float)pos * theta;
    float c = cosf(ang), s = sinf(ang);
    long base = (long)r * (nh * 64) + h * 64 + d;
    float x1 = buf[base], x2 = buf[base + 32];
    buf[base]      = x1 * c - x2 * s;
    buf[base + 32] = x2 * c + x1 * s;
}

// ---- MFMA flash attention (R4 structure); epilogue emits aout hi/lo ----
constexpr int APS = 72;
__global__ __launch_bounds__(256) void k_attn(const float* __restrict__ q, const float* __restrict__ k,
                       const float* __restrict__ v, unsigned short* __restrict__ aoH,
                       unsigned short* __restrict__ aoL) {
    int bx = blockIdx.x, h = blockIdx.y, b = blockIdx.z;
    int hk = h >> 2;
    int qb0 = bx * 64;
    int tid = threadIdx.x, lane = tid & 63, wid = tid >> 6;
    int quad = lane >> 4, l16 = lane & 15;
    __shared__ alignas(16) unsigned short LdsA[9216], LdsB[9216];
    unsigned short* Kh = LdsA;          unsigned short* Kl = LdsB;
    unsigned short* Ph = LdsA;          unsigned short* Pl = LdsB;
    unsigned short* Vth = LdsA + 4608;  unsigned short* Vtl = LdsB + 4608;

    int qrow = qb0 + wid * 16 + l16;
    short8 qh[2], ql[2];
    #pragma unroll
    for (int ks = 0; ks < 2; ks++) {
        const float* qp = q + ((long)(b * KCn + qrow)) * (NHn * HDn) + h * HDn + ks * 32 + quad * 8;
        float tmp[8];
        *(float4*)tmp = *(const float4*)qp;
        *(float4*)(tmp + 4) = *(const float4*)(qp + 4);
        #pragma unroll
        for (int j = 0; j < 8; j++) {
            unsigned short hh, ll;
            cvt_hilo(tmp[j], hh, ll);
            qh[ks][j] = (short)hh; ql[ks][j] = (short)ll;
        }
    }

    floatx4 sacc[16];
    #pragma unroll
    for (int t = 0; t < 16; t++) sacc[t] = (floatx4){0.f, 0.f, 0.f, 0.f};

    int qmax = qb0 + 63;
    int nkc = qmax / 128 + 1;
    for (int kc = 0; kc < nkc; kc++) {
        __syncthreads();
        {
            int r = tid >> 1, dh = (tid & 1) * 32;
            const float* kp = k + ((long)(b * KCn + kc * 128 + r)) * (NKVn * HDn) + hk * HDn + dh;
            #pragma unroll
            for (int f = 0; f < 8; f++) {
                float tmp[4];
                *(float4*)tmp = *(const float4*)(kp + f * 4);
                unsigned short h0, h1, h2, h3, l0, l1, l2, l3;
                cvt_hilo(tmp[0], h0, l0); cvt_hilo(tmp[1], h1, l1);
                cvt_hilo(tmp[2], h2, l2); cvt_hilo(tmp[3], h3, l3);
                *(ushort4*)&Kh[r * APS + dh + f * 4] = make_ushort4(h0, h1, h2, h3);
                *(ushort4*)&Kl[r * APS + dh + f * 4] = make_ushort4(l0, l1, l2, l3);
            }
        }
        __syncthreads();
        #pragma unroll
        for (int tj = 0; tj < 8; tj++) {
            int kr = tj * 16 + l16;
            int gt = kc * 8 + tj;
            #pragma unroll
            for (int ks = 0; ks < 2; ks++) {
                short8 bh0 = *(const short8*)&Kh[kr * APS + ks * 32 + quad * 8];
                short8 bl0 = *(const short8*)&Kl[kr * APS + ks * 32 + quad * 8];
                sacc[gt] = __builtin_amdgcn_mfma_f32_16x16x32_bf16(qh[ks], bh0, sacc[gt], 0, 0, 0);
                sacc[gt] = __builtin_amdgcn_mfma_f32_16x16x32_bf16(qh[ks], bl0, sacc[gt], 0, 0, 0);
                sacc[gt] = __builtin_amdgcn_mfma_f32_16x16x32_bf16(ql[ks], bh0, sacc[gt], 0, 0, 0);
            }
        }
    }

    float rowinv[4];
    #pragma unroll
    for (int r = 0; r < 4; r++) {
        int qg = qb0 + wid * 16 + quad * 4 + r;
        float mm = -3.4e38f;
        #pragma unroll
        for (int t = 0; t < 16; t++) {
            int key = t * 16 + l16;
            float s = (key <= qg) ? sacc[t][r] * 0.125f : -1e30f;
            sacc[t][r] = s;
            mm = fmaxf(mm, s);
        }
        #pragma unroll
        for (int o = 1; o < 16; o <<= 1) mm = fmaxf(mm, __shfl_xor(mm, o));
        float zz = 0.f;
        #pragma unroll
        for (int t = 0; t < 16; t++) {
            float e = expf(sacc[t][r] - mm);
            sacc[t][r] = e; zz += e;
        }
        #pragma unroll
        for (int o = 1; o < 16; o <<= 1) zz += __shfl_xor(zz, o);
        rowinv[r] = 1.f / zz;
    }

    floatx4 oacc[4];
    #pragma unroll
    for (int dt = 0; dt < 4; dt++) oacc[dt] = (floatx4){0.f, 0.f, 0.f, 0.f};
    int npv = qmax / 64 + 1;
    for (int c4 = 0; c4 < npv; c4++) {
        __syncthreads();
        {
            #pragma unroll
            for (int it = 0; it < 4; it++) {
                int task = tid + 256 * it;
                int kloc = task & 63, d4 = (task >> 6) * 4;
                float tmp[4];
                *(float4*)tmp = *(const float4*)(v + ((long)(b * KCn + c4 * 64 + kloc)) * (NKVn * HDn) + hk * HDn + d4);
                #pragma unroll
                for (int i = 0; i < 4; i++) {
                    unsigned short hh, ll;
                    cvt_hilo(tmp[i], hh, ll);
                    Vth[(d4 + i) * APS + kloc] = hh;
                    Vtl[(d4 + i) * APS + kloc] = ll;
                }
            }
        }
        #pragma unroll
        for (int tt = 0; tt < 4; tt++) {
            int t = c4 * 4 + tt;
            #pragma unroll
            for (int r = 0; r < 4; r++) {
                int row = wid * 16 + quad * 4 + r;
                float pv2 = sacc[t][r] * rowinv[r];
                unsigned short hh, ll;
                cvt_hilo(pv2, hh, ll);
                Ph[row * APS + tt * 16 + l16] = hh;
                Pl[row * APS + tt * 16 + l16] = ll;
            }
        }
        __syncthreads();
        short8 pah[2], pal[2];
        #pragma unroll
        for (int ks = 0; ks < 2; ks++) {
            pah[ks] = *(const short8*)&Ph[(wid * 16 + l16) * APS + ks * 32 + quad * 8];
            pal[ks] = *(const short8*)&Pl[(wid * 16 + l16) * APS + ks * 32 + quad * 8];
        }
        #pragma unroll
        for (int dt = 0; dt < 4; dt++) {
            #pragma unroll
            for (int ks = 0; ks < 2; ks++) {
                short8 vbh = *(const short8*)&Vth[(dt * 16 + l16) * APS + ks * 32 + quad * 8];
                short8 vbl = *(const short8*)&Vtl[(dt * 16 + l16) * APS + ks * 32 + quad * 8];
                oacc[dt] = __builtin_amdgcn_mfma_f32_16x16x32_bf16(pah[ks], vbh, oacc[dt], 0, 0, 0);
                oacc[dt] = __builtin_amdgcn_mfma_f32_16x16x32_bf16(pah[ks], vbl, oacc[dt], 0, 0, 0);
                oacc[dt] = __builtin_amdgcn_mfma_f32_16x16x32_bf16(pal[ks], vbh, oacc[dt], 0, 0, 0);
            }
        }
    }

    #pragma unroll
    for (int dt = 0; dt < 4; dt++) {
        #pragma unroll
        for (int r = 0; r < 4; r++) {
            int row = qb0 + wid * 16 + quad * 4 + r;
            long idx = ((long)(b * KCn + row)) * (NHn * HDn) + h * HDn + dt * 16 + l16;
            unsigned short hh, ll;
            cvt_hilo(oacc[dt][r], hh, ll);
            aoH[idx] = hh; aoL[idx] = ll;
        }
    }
}

// ---- x2 = xs + ao; h2 = rmsnorm(x2, ln2) emitted hi/lo ----
__global__ void k_add_ln2(const float* __restrict__ xs, const float* __restrict__ ao,
                          const float* __restrict__ w, unsigned short* __restrict__ h2H,
                          unsigned short* __restrict__ h2L) {
    int r = blockIdx.x;
    __shared__ float red[4];
    float v[4]; float ss = 0.f;
    #pragma unroll
    for (int j = 0; j < 4; j++) {
        int d = threadIdx.x + j * 256;
        float x = xs[(long)r * Dn + d] + ao[(long)r * Dn + d];
        v[j] = x; ss += x * x;
    }
    ss = blk_sum256(ss, red);
    float sc = 1.f / sqrtf(ss * (1.f / Dn) + 1e-6f);
    #pragma unroll
    for (int j = 0; j < 4; j++) {
        int d = threadIdx.x + j * 256;
        unsigned short hh, ll;
        cvt_hilo(v[j] * sc * w[d], hh, ll);
        h2H[(long)r * Dn + d] = hh;
        h2L[(long)r * Dn + d] = ll;
    }
}

// ---- silu(g)*u -> hi/lo ----
__global__ void k_silu_mul(const float* __restrict__ gact, const float* __restrict__ uact,
                           unsigned short* __restrict__ oh, unsigned short* __restrict__ ol, int n) {
    int i = blockIdx.x * blockDim.x + threadIdx.x;
    if (i < n) {
        float x = gact[i];
        unsigned short hh, ll;
        cvt_hilo(x * sigmf(x) * uact[i], hh, ll);
        oh[i] = hh; ol[i] = ll;
    }
}

// ---- xp[b, sel[b,j], :] += g * (ao + ff). block per (b,j) ----
__global__ void k_scatter(float* __restrict__ xp, const float* __restrict__ ao,
                          const float* __restrict__ ff, const float* __restrict__ g,
                          const int* __restrict__ sel) {
    int r = blockIdx.x;
    int b = r / KCn;
    int p = sel[r];
    float gg = g[r];
    float* dst = xp + ((long)b * Pn + p) * Dn;
    #pragma unroll
    for (int j = 0; j < 4; j++) {
        int d = threadIdx.x + j * 256;
        dst[d] += gg * (ao[(long)r * Dn + d] + ff[(long)r * Dn + d]);
    }
}

// ---- win = sigmoid(gelu(hmlp) @ w2 + b2) ----
__global__ void k_win(const float* __restrict__ hmlp, const float* __restrict__ w2,
                      const float* __restrict__ b2, float* __restrict__ win) {
    int tid = blockIdx.x * blockDim.x + threadIdx.x;
    if (tid >= Bn * Pn * Sn) return;
    int s = tid & 3; int r = tid >> 2;
    float acc = b2[s];
    const float* hr = hmlp + (long)r * 256;
    for (int i = 0; i < 256; i++) acc += geluf(hr[i]) * w2[i * 4 + s];
    win[tid] = sigmf(acc);
}

// ---- y = rmsnorm(proj*win, dec_norm_w) emitted hi/lo ----
__global__ void k_dec_norm(const float* __restrict__ proj, const float* __restrict__ win,
                           const float* __restrict__ w, unsigned short* __restrict__ yH,
                           unsigned short* __restrict__ yL) {
    int r = blockIdx.x;
    float wv = win[r];
    __shared__ float red[4];
    float v[4]; float ss = 0.f;
    #pragma unroll
    for (int j = 0; j < 4; j++) {
        int d = threadIdx.x + j * 256;
        float x = proj[(long)r * Dn + d] * wv;
        v[j] = x; ss += x * x;
    }
    ss = blk_sum256(ss, red);
    float sc = 1.f / sqrtf(ss * (1.f / Dn) + 1e-6f);
    #pragma unroll
    for (int j = 0; j < 4; j++) {
        int d = threadIdx.x + j * 256;
        unsigned short hh, ll;
        cvt_hilo(v[j] * sc * w[d], hh, ll);
        yH[(long)r * Dn + d] = hh;
        yL[(long)r * Dn + d] = ll;
    }
}

extern "C" void kernel_launch(void* const* d_in, const int* in_sizes, int n_in,
                              void* d_out, int out_size, void* d_ws, size_t ws_size,
                              hipStream_t stream) {
    const int*   tokens     = (const int*)  d_in[0];
    const float* emb        = (const float*)d_in[1];
    const float* bp_w1      = (const float*)d_in[2];
    const float* bp_b1      = (const float*)d_in[3];
    const float* bp_w2      = (const float*)d_in[4];
    const float* bp_b2      = (const float*)d_in[5];
    const float* enc_norm_w = (const float*)d_in[6];
    const float* router_w   = (const float*)d_in[7];
    const float* ln1_w      = (const float*)d_in[8];
    const float* ln2_w      = (const float*)d_in[9];
    const float* q_w        = (const float*)d_in[10];
    const float* k_w        = (const float*)d_in[11];
    const float* v_w        = (const float*)d_in[12];
    const float* o_w        = (const float*)d_in[13];
    const float* gate_w     = (const float*)d_in[14];
    const float* up_w       = (const float*)d_in[15];
    const float* down_w     = (const float*)d_in[16];
    const float* dec_proj_w = (const float*)d_in[17];
    const float* dec_proj_b = (const float*)d_in[18];
    const float* dec_mlp_w1 = (const float*)d_in[19];
    const float* dec_mlp_b1 = (const float*)d_in[20];
    const float* dec_mlp_w2 = (const float*)d_in[21];
    const float* dec_mlp_b2 = (const float*)d_in[22];
    const float* dec_norm_w = (const float*)d_in[23];
    const float* head_w     = (const float*)d_in[24];
    float* out = (float*)d_out;

    float* W = (float*)d_ws;
    float* EW   = W + OFF_EW;
    float* cA   = W + OFF_CA;
    float* cB   = W + OFF_CB;
    float* cC   = W + OFF_CC;
    float* ent  = W + OFF_ENT;
    int*   idxb = (int*)(W + OFF_IDX);
    float* xp   = W + OFF_XP;
    float* rl   = W + OFF_RL;
    int*   sel  = (int*)(W + OFF_SEL);
    float* g    = W + OFF_G;
    float* scr  = W + SCR;
    float* xs   = scr + SC_XS;
    unsigned short* hH = (unsigned short*)(scr + SC_H);
    unsigned short* hL = hH + 1048576;
    float* qb   = scr + SC_Q;
    float* kb   = scr + SC_K;
    float* vb   = scr + SC_V;
    unsigned short* aoutH = (unsigned short*)(scr + SC_AOUT);
    unsigned short* aoutL = aoutH + 1048576;
    float* ao   = scr + SC_AO;
    unsigned short* h2H = (unsigned short*)(scr + SC_H2);
    unsigned short* h2L = h2H + 1048576;
    float* gact = scr + SC_GACT;
    float* uact = scr + SC_UACT;
    float* ffb  = scr + SC_FF;
    float* proj = scr + SC_PROJ;
    float* hmlp = scr + SC_HMLP;
    float* win  = scr + SC_WIN;
    unsigned short* yH = (unsigned short*)(scr + SC_Y);
    unsigned short* yL = yH + 8388608;
    unsigned short* WTh = (unsigned short*)(W + OFF_WT);
    unsigned short* WTl = WTh + 4194304;
    float* parts = W + OFF_PARTS;
    unsigned short* ghH = (unsigned short*)(W + OFF_GHL);
    unsigned short* ghL = ghH + 4194304;          // layer: gact_hl (4M elems)
    unsigned short* xpH = (unsigned short*)(W + OFF_GHL);
    unsigned short* xpL = xpH + 2097152;          // decoder: xp_hl (2M elems)

    // byte-patch encoder
    k_ew<<<dim3(96, 17), dim3(16, 16), 0, stream>>>(emb, bp_w1, EW);
    k_conv1<<<Bn * Tn / 4, 256, 0, stream>>>(tokens, EW, bp_b1, bp_w2, cA, cB, cC);
    k_patchstats<<<(Bn * Pn + 255) / 256, 256, 0, stream>>>(cA, cB, cC, bp_b2, ent, idxb);
    k_xp<<<Bn * Pn, 256, 0, stream>>>(tokens, idxb, emb, enc_norm_w, xp);

    for (int l = 0; l < Ln; l++) {
        k_router<<<Bn * Pn, 256, 0, stream>>>(xp, router_w + (long)l * Dn, ent, rl);
        k_topk<<<Bn, Pn, 0, stream>>>(rl, sel, g);
        k_gather_ln1<<<Bn * KCn, 256, 0, stream>>>(xp, sel, ln1_w + (long)l * Dn, xs, hH, hL);

        k_wconv<<<dim3(32, 32), 256, 0, stream>>>(q_w + (long)l * Dn * Dn, WTh, WTl, 1024, 1024);
        k_mfma2<<<dim3(8, 8, 4), 256, 0, stream>>>(hH, hL, WTh, WTl, nullptr, nullptr, 1024, 1024, 1024, 4, parts);
        k_reduce<<<4096, 256, 0, stream>>>(parts, qb, nullptr, 1048576, 4, 1024);

        k_wconv<<<dim3(8, 32), 256, 0, stream>>>(k_w + (long)l * Dn * 256, WTh, WTl, 1024, 256);
        k_mfma2<<<dim3(2, 8, 8), 256, 0, stream>>>(hH, hL, WTh, WTl, nullptr, nullptr, 1024, 256, 1024, 8, parts);
        k_reduce<<<1024, 256, 0, stream>>>(parts, kb, nullptr, 262144, 8, 256);

        k_wconv<<<dim3(8, 32), 256, 0, stream>>>(v_w + (long)l * Dn * 256, WTh, WTl, 1024, 256);
        k_mfma2<<<dim3(2, 8, 8), 256, 0, stream>>>(hH, hL, WTh, WTl, nullptr, nullptr, 1024, 256, 1024, 8, parts);
        k_reduce<<<1024, 256, 0, stream>>>(parts, vb, nullptr, 262144, 8, 256);

        k_rope<<<(Bn * KCn * NHn * 32 + 255) / 256, 256, 0, stream>>>(qb, sel, NHn);
        k_rope<<<(Bn * KCn * NKVn * 32 + 255) / 256, 256, 0, stream>>>(kb, sel, NKVn);
        k_attn<<<dim3(4, NHn, Bn), 256, 0, stream>>>(qb, kb, vb, aoutH, aoutL);

        k_wconv<<<dim3(32, 32), 256, 0, stream>>>(o_w + (long)l * Dn * Dn, WTh, WTl, 1024, 1024);
        k_mfma2<<<dim3(8, 8, 4), 256, 0, stream>>>(aoutH, aoutL, WTh, WTl, nullptr, nullptr, 1024, 1024, 1024, 4, parts);
        k_reduce<<<4096, 256, 0, stream>>>(parts, ao, nullptr, 1048576, 4, 1024);

        k_add_ln2<<<Bn * KCn, 256, 0, stream>>>(xs, ao, ln2_w + (long)l * Dn, h2H, h2L);

        k_wconv<<<dim3(128, 32), 256, 0, stream>>>(gate_w + (long)l * Dn * FFn, WTh, WTl, 1024, 4096);
        k_mfma2<<<dim3(32, 8, 1), 256, 0, stream>>>(h2H, h2L, WTh, WTl, gact, nullptr, 1024, 4096, 1024, 1, parts);
        k_wconv<<<dim3(128, 32), 256, 0, stream>>>(up_w + (long)l * Dn * FFn, WTh, WTl, 1024, 4096);
        k_mfma2<<<dim3(32, 8, 1), 256, 0, stream>>>(h2H, h2L, WTh, WTl, uact, nullptr, 1024, 4096, 1024, 1, parts);

        k_silu_mul<<<(Bn * KCn * FFn + 255) / 256, 256, 0, stream>>>(gact, uact, ghH, ghL, Bn * KCn * FFn);

        k_wconv<<<dim3(32, 128), 256, 0, stream>>>(down_w + (long)l * FFn * Dn, WTh, WTl, 4096, 1024);
        k_mfma2<<<dim3(8, 8, 4), 256, 0, stream>>>(ghH, ghL, WTh, WTl, nullptr, nullptr, 1024, 1024, 4096, 4, parts);
        k_reduce<<<4096, 256, 0, stream>>>(parts, ffb, nullptr, 1048576, 4, 1024);

        k_scatter<<<Bn * KCn, 256, 0, stream>>>(xp, ao, ffb, g, sel);
    }

    // decoder
    k_aconv<<<8192, 256, 0, stream>>>(xp, xpH, xpL, 2097152);
    k_wconv<<<dim3(128, 32), 256, 0, stream>>>(dec_proj_w, WTh, WTl, 1024, 4096);
    k_mfma2<<<dim3(32, 16, 1), 256, 0, stream>>>(xpH, xpL, WTh, WTl, proj, dec_proj_b, 2048, 4096, 1024, 1, parts);
    k_wconv<<<dim3(8, 32), 256, 0, stream>>>(dec_mlp_w1, WTh, WTl, 1024, 256);
    k_mfma2<<<dim3(2, 16, 4), 256, 0, stream>>>(xpH, xpL, WTh, WTl, nullptr, nullptr, 2048, 256, 1024, 4, parts);
    k_reduce<<<2048, 256, 0, stream>>>(parts, hmlp, dec_mlp_b1, 524288, 4, 256);
    k_win<<<(Bn * Pn * Sn + 255) / 256, 256, 0, stream>>>(hmlp, dec_mlp_w2, dec_mlp_b2, win);
    k_dec_norm<<<Bn * Pn * Sn, 256, 0, stream>>>(proj, win, dec_norm_w, yH, yL);
    k_wconv<<<dim3(9, 32), 256, 0, stream>>>(head_w, WTh, WTl, 1024, 257);
    k_mfma2<<<dim3(3, 64, 2), 256, 0, stream>>>(yH, yL, WTh, WTl, nullptr, nullptr, 8192, 257, 1024, 2, parts);
    k_reduce<<<8224, 256, 0, stream>>>(parts, out, nullptr, 2105344, 2, 257);
}